// Round 11
// baseline (184.565 us; speedup 1.0000x reference)
//
#include <hip/hip_runtime.h>
#include <stdint.h>

typedef unsigned short u16;
typedef unsigned int u32;
typedef short bf16x8 __attribute__((ext_vector_type(8)));
typedef float f32x4 __attribute__((ext_vector_type(4)));

#define MFMA16(a, b, c) __builtin_amdgcn_mfma_f32_16x16x32_bf16((a), (b), (c), 0, 0, 0)

__device__ __forceinline__ u16 f2bf(float f) {
  union { float f; u32 u; } v; v.f = f;
  u32 u = v.u;
  u32 r = (u + 0x7FFFu + ((u >> 16) & 1u)) >> 16;  // RNE
  return (u16)r;
}
__device__ __forceinline__ float bf2f(u16 h) {
  union { u32 u; float f; } v; v.u = ((u32)h) << 16;
  return v.f;
}
// packed f32x2 -> bf16x2 (single HW instruction, RNE)
__device__ __forceinline__ u32 cvtpk_bf16(float lo, float hi) {
  u32 r;
  asm("v_cvt_pk_bf16_f32 %0, %1, %2" : "=v"(r) : "v"(lo), "v"(hi));
  return r;
}

// async global->LDS, 16B per lane. LDS base must be wave-uniform (HW adds lane*16).
__device__ __forceinline__ void gload_lds16(const void* g, void* l) {
  __builtin_amdgcn_global_load_lds(
      (const __attribute__((address_space(1))) unsigned int*)g,
      (__attribute__((address_space(3))) unsigned int*)l,
      16, 0, 0);
}

// ---------------- convert fp32 -> bf16 (vectorized, cvt_pk) ----------------
__global__ __launch_bounds__(256) void cvt_f32_bf16(
    const float* __restrict__ src, u16* __restrict__ dst, int n4) {
  int i = blockIdx.x * 256 + threadIdx.x;
  if (i >= n4) return;
  float4 v = reinterpret_cast<const float4*>(src)[i];
  uint2 o;
  o.x = cvtpk_bf16(v.x, v.y);
  o.y = cvtpk_bf16(v.z, v.w);
  reinterpret_cast<uint2*>(dst)[i] = o;
}

// ---------------- transpose+convert: src f32 [R][C] -> dst bf16 [C][R] ----------------
__global__ __launch_bounds__(256) void transpose_f32_bf16(
    const float* __restrict__ src, u16* __restrict__ dst, int R, int C) {
  __shared__ u16 t[32][33];
  const int bx = blockIdx.x * 32, by = blockIdx.y * 32;
  const int tx = threadIdx.x & 31, ty = threadIdx.x >> 5;  // 32x8
#pragma unroll
  for (int i = 0; i < 32; i += 8)
    t[ty + i][tx] = f2bf(src[(size_t)(by + ty + i) * C + bx + tx]);
  __syncthreads();
#pragma unroll
  for (int i = 0; i < 32; i += 8)
    dst[(size_t)(bx + ty + i) * R + by + tx] = t[tx][ty + i];
}

// ---------------- GEMM: C[M][N] = A[M][K] * Bt[N][K]^T + bias ----------------
// 1D grid + bijective XCD swizzle (nwg % 8 == 0 for all our launches).
template <bool OUT_BF16>
__global__ __launch_bounds__(256) void gemm_bf16(
    const u16* __restrict__ A, const u16* __restrict__ Bt,
    const float* __restrict__ bias, void* __restrict__ Cout,
    int M, int N, int K) {
  __shared__ __align__(16) u16 As[128 * 64];
  __shared__ __align__(16) u16 Bs[128 * 64];
  const int tid = threadIdx.x;
  const int lane = tid & 63;
  const int wave = tid >> 6;
  const int nwg = gridDim.x;
  const int id = blockIdx.x;
  const int sw = (id & 7) * (nwg >> 3) + (id >> 3);
  const int nx = N >> 7;
  const int m0 = (sw / nx) * 128;
  const int n0 = (sw % nx) * 128;
  const int wm = (wave >> 1) * 64;
  const int wn = (wave & 1) * 64;

  f32x4 acc[4][4] = {};

  const char* Abase = (const char*)A;
  const char* Bbase = (const char*)Bt;

  for (int kt = 0; kt < K; kt += 64) {
    __syncthreads();
#pragma unroll
    for (int i = 0; i < 4; ++i) {
      int flat = wave * 1024 + lane * 16 + i * 4096;
      int row = flat >> 7;
      int colb = flat & 127;
      gload_lds16(Abase + ((size_t)(m0 + row) * K + kt) * 2 + colb,
                  (char*)As + flat);
      gload_lds16(Bbase + ((size_t)(n0 + row) * K + kt) * 2 + colb,
                  (char*)Bs + flat);
    }
    __syncthreads();
#pragma unroll
    for (int ks = 0; ks < 2; ++ks) {
      const int col = (lane >> 4) * 8 + ks * 32;
      bf16x8 af[4], bfr[4];
#pragma unroll
      for (int mt = 0; mt < 4; ++mt)
        af[mt] = *(const bf16x8*)(As + (wm + mt * 16 + (lane & 15)) * 64 + col);
#pragma unroll
      for (int nt = 0; nt < 4; ++nt)
        bfr[nt] = *(const bf16x8*)(Bs + (wn + nt * 16 + (lane & 15)) * 64 + col);
#pragma unroll
      for (int mt = 0; mt < 4; ++mt)
#pragma unroll
        for (int nt = 0; nt < 4; ++nt)
          acc[mt][nt] = MFMA16(af[mt], bfr[nt], acc[mt][nt]);
    }
  }

  float bv[4];
#pragma unroll
  for (int nt = 0; nt < 4; ++nt)
    bv[nt] = bias[n0 + wn + nt * 16 + (lane & 15)];
#pragma unroll
  for (int mt = 0; mt < 4; ++mt)
#pragma unroll
    for (int nt = 0; nt < 4; ++nt)
#pragma unroll
      for (int r = 0; r < 4; ++r) {
        int m = m0 + wm + mt * 16 + (lane >> 4) * 4 + r;
        int n = n0 + wn + nt * 16 + (lane & 15);
        float v = acc[mt][nt][r] + bv[nt];
        if (OUT_BF16)
          ((u16*)Cout)[(size_t)m * N + n] = f2bf(v);
        else
          ((float*)Cout)[(size_t)m * N + n] = v;
      }
}

// ------- out-proj GEMM with fused split-combine on the A path -------
// A[m][k] = (part0[m][k] + part1[m][k]) / (l0(m,h) + l1(m,h)),  h = k>>6.
// A is reg-staged (global vec loads -> cvt_pk -> ds_write_b128); B via gload_lds.
__global__ __launch_bounds__(256) void gemm_out_fused(
    const u16* __restrict__ part, const float* __restrict__ Ml,
    const u16* __restrict__ Bt, const float* __restrict__ bias,
    float* __restrict__ Cout, int M, int N, int K) {
  __shared__ __align__(16) u16 As[128 * 64];
  __shared__ __align__(16) u16 Bs[128 * 64];
  const int tid = threadIdx.x;
  const int lane = tid & 63;
  const int wave = tid >> 6;
  const int nwg = gridDim.x;
  const int id = blockIdx.x;
  const int sw = (id & 7) * (nwg >> 3) + (id >> 3);
  const int nx = N >> 7;
  const int m0 = (sw / nx) * 128;
  const int n0 = (sw % nx) * 128;
  const int wm = (wave >> 1) * 64;
  const int wn = (wave & 1) * 64;

  f32x4 acc[4][4] = {};
  const char* Bbase = (const char*)Bt;

  for (int kt = 0; kt < K; kt += 64) {
    __syncthreads();
    const int hcol = kt >> 6;
    bf16x8 p0[4], p1[4];
    float inv[4];
#pragma unroll
    for (int i = 0; i < 4; ++i) {
      int flat = wave * 1024 + lane * 16 + i * 4096;
      int row = flat >> 7;
      int colb = flat & 127;
      gload_lds16(Bbase + ((size_t)(n0 + row) * K + kt) * 2 + colb,
                  (char*)Bs + flat);
      int m = m0 + row;
      const u16* pa = part + (size_t)m * 1024 + kt + (colb >> 1);
      p0[i] = *(const bf16x8*)pa;
      p1[i] = *(const bf16x8*)(pa + (size_t)4096 * 1024);
      int i0 = ((m >> 11) * 16 + hcol) * 2048 + (m & 2047);
      inv[i] = 1.f / (Ml[i0] + Ml[i0 + 65536]);
    }
#pragma unroll
    for (int i = 0; i < 4; ++i) {
      int flat = wave * 1024 + lane * 16 + i * 4096;
      union { u32 w[4]; bf16x8 v; } o;
#pragma unroll
      for (int j = 0; j < 4; ++j) {
        float a = (bf2f((u16)p0[i][2 * j]) + bf2f((u16)p1[i][2 * j])) * inv[i];
        float b = (bf2f((u16)p0[i][2 * j + 1]) + bf2f((u16)p1[i][2 * j + 1])) * inv[i];
        o.w[j] = cvtpk_bf16(a, b);
      }
      *(bf16x8*)((char*)As + flat) = o.v;
    }
    __syncthreads();
#pragma unroll
    for (int ks = 0; ks < 2; ++ks) {
      const int col = (lane >> 4) * 8 + ks * 32;
      bf16x8 af[4], bfr[4];
#pragma unroll
      for (int mt = 0; mt < 4; ++mt)
        af[mt] = *(const bf16x8*)(As + (wm + mt * 16 + (lane & 15)) * 64 + col);
#pragma unroll
      for (int nt = 0; nt < 4; ++nt)
        bfr[nt] = *(const bf16x8*)(Bs + (wn + nt * 16 + (lane & 15)) * 64 + col);
#pragma unroll
      for (int mt = 0; mt < 4; ++mt)
#pragma unroll
        for (int nt = 0; nt < 4; ++nt)
          acc[mt][nt] = MFMA16(af[mt], bfr[nt], acc[mt][nt]);
    }
  }

  float bv[4];
#pragma unroll
  for (int nt = 0; nt < 4; ++nt)
    bv[nt] = bias[n0 + wn + nt * 16 + (lane & 15)];
#pragma unroll
  for (int mt = 0; mt < 4; ++mt)
#pragma unroll
    for (int nt = 0; nt < 4; ++nt)
#pragma unroll
      for (int r = 0; r < 4; ++r) {
        int m = m0 + wm + mt * 16 + (lane >> 4) * 4 + r;
        int n = n0 + wn + nt * 16 + (lane & 15);
        Cout[(size_t)m * N + n] = acc[mt][nt][r] + bv[nt];
      }
}

// ---------------- flash attention (v11: XCD-affinity grid, 128-key stages) ----
// 1D grid; id = (hz&7) + 8*(q + 8*(hz>>3)), hz = h*NZ+z  -> the 8 q-blocks of
// one (h,z) share one XCD's L2 for their K/V panel (kills cross-XCD re-fetch).
// Math identical to v10: S^T = mfma(K,Q), m=0 softmax, mask via zero-V +
// MFMA row-sum with LDS-LUT mask fragments, 128-key double-buffered stages.
// NOTE (round-5 lesson): no min-waves clause in __launch_bounds__ (spills).
#define T_SEQ 2048
#define ROWQKV 3072
#define SCL 0.180336880f  /* (1/sqrt(64)) * log2(e) */

template <bool SPLIT>
__global__ __launch_bounds__(512) void attn_fwd(
    const u16* __restrict__ qkv, const int* __restrict__ mask,
    u16* __restrict__ outp, float* __restrict__ Ml, int nk) {
  __shared__ __align__(16) u16 Ks[2][2][64 * 64];  // [buf][half][key][dk], swz s=row&7
  __shared__ __align__(16) u16 Vt[2][2][64 * 64];  // [buf][half][d][key], swz row^(row>>3)
  __shared__ u32 mkb[64];                          // key-mask bitset (nk bits used)
  __shared__ __align__(16) u32 lut[256 * 4];       // byte -> 8 x bf16 {0,1}

  const int tid = threadIdx.x;
  const int lane = tid & 63;
  const int wave = tid >> 6;
  const int r15 = lane & 15;
  const int g = lane >> 4;
  const bool hi = (g >> 1) != 0;
  // XCD-affinity decode
  const int id = blockIdx.x;
  const int hz = ((id >> 6) << 3) | (id & 7);  // group = id>>6, c = id&7
  const int qb = (id >> 3) & 7;
  const int h = SPLIT ? (hz >> 2) : (hz >> 1);
  const int z = SPLIT ? (hz & 3) : (hz & 1);
  const int split = SPLIT ? (z >> 1) : 0;
  const int b = SPLIT ? (z & 1) : z;
  const int s0 = split * nk;
  const int q0 = qb * 256 + wave * 32;
  const size_t rowb = (size_t)b * T_SEQ;

  // mask bitset via wave ballots (keys s0 .. s0+nk-1)
  for (int i = wave; i < (nk >> 6); i += 8) {
    unsigned long long bm =
        __ballot(mask[b * T_SEQ + s0 + i * 64 + lane] != 0);
    if (lane == 0) {
      mkb[2 * i] = (u32)bm;
      mkb[2 * i + 1] = (u32)(bm >> 32);
    }
  }
  // build mask LUT: lut[byte] = 8 bf16 (elem j = bit j ? 1.0 : 0.0)
  for (int i = tid; i < 256; i += 512) {
    union { u32 w[4]; bf16x8 v; } e;
#pragma unroll
    for (int j = 0; j < 4; ++j)
      e.w[j] = (((i >> (2 * j)) & 1) ? 0x3F80u : 0u) |
               (((i >> (2 * j + 1)) & 1) ? 0x3F800000u : 0u);
    *(bf16x8*)((char*)lut + i * 16) = e.v;
  }

  // Q fragments (B-operand of S^T = K·Q^T), pre-scaled
  bf16x8 aq[2][2];
#pragma unroll
  for (int mt = 0; mt < 2; ++mt)
#pragma unroll
    for (int ks = 0; ks < 2; ++ks) {
      bf16x8 t = *(const bf16x8*)(qkv +
          (rowb + q0 + mt * 16 + r15) * ROWQKV + h * 64 + g * 8 + ks * 32);
#pragma unroll
      for (int j = 0; j < 8; ++j) t[j] = (short)f2bf(bf2f((u16)t[j]) * SCL);
      aq[mt][ks] = t;
    }

  f32x4 accO[2][4] = {};
  f32x4 ssum[2] = {};
  bf16x8 vr0, vr1;

#define ISSUE_K2(ktile, buf)                                                   \
  {                                                                            \
    int L = wave * 1024 + lane * 16;                                           \
    int row = L >> 7;                                                          \
    int cb = L & 127;                                                          \
    int scb = cb ^ ((row & 7) << 4);                                           \
    gload_lds16((const char*)qkv +                                             \
                    ((rowb + (ktile) + row) * ROWQKV + 1024 + h * 64) * 2 + scb, \
                (char*)&Ks[buf][0][0] + wave * 1024);                          \
    gload_lds16((const char*)qkv +                                             \
                    ((rowb + (ktile) + 64 + row) * ROWQKV + 1024 + h * 64) * 2 + scb, \
                (char*)&Ks[buf][1][0] + wave * 1024);                          \
  }

#define LOAD_V2(ktile)                                                         \
  {                                                                            \
    vr0 = *(const bf16x8*)(qkv + (rowb + (ktile) + (tid >> 3)) * ROWQKV +      \
                           2048 + h * 64 + (tid & 7) * 8);                     \
    vr1 = *(const bf16x8*)(qkv + (rowb + (ktile) + 64 + (tid >> 3)) * ROWQKV + \
                           2048 + h * 64 + (tid & 7) * 8);                     \
  }

#define WRITE_V2(buf, t4)                                                      \
  {                                                                            \
    int key = tid >> 3;                                                        \
    u32 w0 = mkb[(t4) + (key >> 5)];                                           \
    if (!((w0 >> (key & 31)) & 1u)) {                                          \
      bf16x8 zz = {};                                                          \
      vr0 = zz;                                                                \
    }                                                                          \
    u32 w1 = mkb[(t4) + 2 + (key >> 5)];                                       \
    if (!((w1 >> (key & 31)) & 1u)) {                                          \
      bf16x8 zz = {};                                                          \
      vr1 = zz;                                                                \
    }                                                                          \
    _Pragma("unroll") for (int j = 0; j < 8; ++j) {                            \
      int row = (tid & 7) * 8 + j;                                             \
      int sv = ((row ^ (row >> 3)) & 7) << 4;                                  \
      *(u16*)((char*)&Vt[buf][0][0] + row * 128 + ((key * 2) ^ sv)) =          \
          (u16)vr0[j];                                                         \
      *(u16*)((char*)&Vt[buf][1][0] + row * 128 + ((key * 2) ^ sv)) =          \
          (u16)vr1[j];                                                         \
    }                                                                          \
  }

#define COMPUTE_HALF(H, bw)                                                    \
  {                                                                            \
    f32x4 s[2][4] = {};                                                        \
    _Pragma("unroll") for (int ks = 0; ks < 2; ++ks) {                         \
      bf16x8 bk[4];                                                            \
      _Pragma("unroll") for (int nt = 0; nt < 4; ++nt) {                       \
        int row = nt * 16 + r15;                                               \
        int cb = (g * 8 + ks * 32) * 2;                                        \
        bk[nt] = *(const bf16x8*)((const char*)&Ks[cur][H][0] + row * 128 +    \
                                  (cb ^ ((row & 7) << 4)));                    \
      }                                                                        \
      _Pragma("unroll") for (int mt = 0; mt < 2; ++mt)                         \
        _Pragma("unroll") for (int nt = 0; nt < 4; ++nt)                       \
          s[mt][nt] = MFMA16(bk[nt], aq[mt][ks], s[mt][nt]);                   \
    }                                                                          \
    u32 pk[2][4][2];                                                           \
    _Pragma("unroll") for (int mt = 0; mt < 2; ++mt)                           \
      _Pragma("unroll") for (int nt = 0; nt < 4; ++nt) {                       \
        float e0 = exp2f(s[mt][nt][0]);                                        \
        float e1 = exp2f(s[mt][nt][1]);                                        \
        float e2 = exp2f(s[mt][nt][2]);                                        \
        float e3 = exp2f(s[mt][nt][3]);                                        \
        pk[mt][nt][0] = cvtpk_bf16(e0, e1);                                    \
        pk[mt][nt][1] = cvtpk_bf16(e2, e3);                                    \
      }                                                                        \
    const int srcA = ((g & 1) << 5) + r15;                                     \
    const int srcB = srcA + 16;                                                \
    __builtin_amdgcn_s_setprio(1);                                             \
    _Pragma("unroll") for (int ks = 0; ks < 2; ++ks) {                         \
      const int col = g * 8 + ks * 32;                                         \
      bf16x8 bv[4];                                                            \
      _Pragma("unroll") for (int nt = 0; nt < 4; ++nt) {                       \
        int row = nt * 16 + r15;                                               \
        int sv = ((row ^ (row >> 3)) & 7) << 4;                                \
        bv[nt] = *(const bf16x8*)((const char*)&Vt[cur][H][0] + row * 128 +    \
                                  ((col * 2) ^ sv));                           \
      }                                                                        \
      u32 wb = mkb[(bw) + ks];                                                 \
      u32 lb = (wb >> (g * 8)) & 0xFFu;                                        \
      bf16x8 mf = *(const bf16x8*)((const char*)lut + lb * 16);                \
      _Pragma("unroll") for (int mt = 0; mt < 2; ++mt) {                       \
        u32 a0l = (u32)__shfl((int)pk[mt][2 * ks][0], srcA);                   \
        u32 a0h = (u32)__shfl((int)pk[mt][2 * ks + 1][0], srcA);               \
        u32 a1l = (u32)__shfl((int)pk[mt][2 * ks][1], srcA);                   \
        u32 a1h = (u32)__shfl((int)pk[mt][2 * ks + 1][1], srcA);               \
        u32 b0l = (u32)__shfl((int)pk[mt][2 * ks][0], srcB);                   \
        u32 b0h = (u32)__shfl((int)pk[mt][2 * ks + 1][0], srcB);               \
        u32 b1l = (u32)__shfl((int)pk[mt][2 * ks][1], srcB);                   \
        u32 b1h = (u32)__shfl((int)pk[mt][2 * ks + 1][1], srcB);               \
        union { u32 w[4]; bf16x8 v; } ap;                                      \
        ap.w[0] = hi ? a0h : a0l;                                              \
        ap.w[1] = hi ? a1h : a1l;                                              \
        ap.w[2] = hi ? b0h : b0l;                                              \
        ap.w[3] = hi ? b1h : b1l;                                              \
        _Pragma("unroll") for (int nt = 0; nt < 4; ++nt)                       \
          accO[mt][nt] = MFMA16(ap.v, bv[nt], accO[mt][nt]);                   \
        ssum[mt] = MFMA16(ap.v, mf, ssum[mt]);                                 \
      }                                                                        \
    }                                                                          \
    __builtin_amdgcn_s_setprio(0);                                             \
  }

  // prologue
  ISSUE_K2(s0, 0);
  LOAD_V2(s0);
  __syncthreads();
  WRITE_V2(0, 0);
  asm volatile("s_waitcnt lgkmcnt(0)" ::: "memory");
  __builtin_amdgcn_sched_barrier(0);
  __builtin_amdgcn_s_barrier();
  __builtin_amdgcn_sched_barrier(0);

  const int nt2 = nk >> 7;  // 128-key stages
  int cur = 0;
  for (int t = 0; t < nt2; ++t) {
    const int kt = s0 + t * 128;
    if (t < nt2 - 1) {
      ISSUE_K2(kt + 128, cur ^ 1);
      LOAD_V2(kt + 128);
    }

    COMPUTE_HALF(0, 4 * t);
    COMPUTE_HALF(1, 4 * t + 2);

    if (t < nt2 - 1) {
      asm volatile("s_waitcnt vmcnt(0)" ::: "memory");
      WRITE_V2(cur ^ 1, 4 * (t + 1));
      asm volatile("s_waitcnt lgkmcnt(0)" ::: "memory");
      __builtin_amdgcn_sched_barrier(0);
      __builtin_amdgcn_s_barrier();
      __builtin_amdgcn_sched_barrier(0);
      cur ^= 1;
    }
  }

  if (SPLIT) {
    u16* po = outp + (size_t)split * T_SEQ * 2 * 1024;
#pragma unroll
    for (int mt = 0; mt < 2; ++mt) {
#pragma unroll
      for (int r = 0; r < 4; ++r) {
        int q = q0 + mt * 16 + g * 4 + r;
#pragma unroll
        for (int nt = 0; nt < 4; ++nt)
          po[(rowb + q) * 1024 + h * 64 + nt * 16 + r15] = f2bf(accO[mt][nt][r]);
      }
      if (r15 == 0) {
        int idx = ((split * 2 + b) * 16 + h) * T_SEQ + q0 + mt * 16 + g * 4;
        *(f32x4*)(Ml + idx) = ssum[mt];
      }
    }
  } else {
#pragma unroll
    for (int mt = 0; mt < 2; ++mt)
#pragma unroll
      for (int r = 0; r < 4; ++r) {
        float inv = 1.f / ssum[mt][r];
        int q = q0 + mt * 16 + g * 4 + r;
#pragma unroll
        for (int nt = 0; nt < 4; ++nt)
          outp[(rowb + q) * 1024 + h * 64 + nt * 16 + r15] =
              f2bf(accO[mt][nt][r] * inv);
      }
  }
#undef ISSUE_K2
#undef LOAD_V2
#undef WRITE_V2
#undef COMPUTE_HALF
}

// ---------------- launch ----------------
extern "C" void kernel_launch(void* const* d_in, const int* in_sizes, int n_in,
                              void* d_out, int out_size, void* d_ws, size_t ws_size,
                              hipStream_t stream) {
  const float* x = (const float*)d_in[0];     // [2,2048,1024] f32
  const int* mask = (const int*)d_in[1];      // [2,1,1,2048] int32
  const float* Wqkv = (const float*)d_in[2];  // [1024,3072] f32
  const float* bqkv = (const float*)d_in[3];  // [3072] f32
  const float* Wout = (const float*)d_in[4];  // [1024,1024] f32
  const float* bout = (const float*)d_in[5];  // [1024] f32
  float* out = (float*)d_out;                 // [2,2048,1024] f32

  const int B = 2, T = 2048, H = 1024, M = B * T;

  u16* qkv = (u16*)d_ws;                       // M*3H
  u16* xa = qkv + (size_t)M * 3 * H;           // M*H (x-bf16; att in non-split)
  u16* WtQ = xa + (size_t)M * H;               // 3H*H
  u16* WtO = WtQ + (size_t)3 * H * H;          // H*H
  u16* part = WtO + (size_t)H * H;             // 2 * M*H  (split partials)
  float* Ml = (float*)(part + (size_t)2 * M * H);  // 2*65536 floats (l only)

  const size_t need = ((size_t)M * 3 * H + (size_t)M * H + (size_t)3 * H * H +
                       (size_t)H * H + (size_t)2 * M * H) * 2 +
                      (size_t)2 * 131072 * 4;
  const bool split = ws_size >= need;

  cvt_f32_bf16<<<(M * H / 4 + 255) / 256, 256, 0, stream>>>(x, xa, M * H / 4);
  transpose_f32_bf16<<<dim3(3 * H / 32, H / 32), 256, 0, stream>>>(Wqkv, WtQ, H, 3 * H);
  transpose_f32_bf16<<<dim3(H / 32, H / 32), 256, 0, stream>>>(Wout, WtO, H, H);
  gemm_bf16<true><<<(3 * H / 128) * (M / 128), 256, 0, stream>>>(xa, WtQ, bqkv, qkv, M, 3 * H, H);
  if (split) {
    attn_fwd<true><<<512, 512, 0, stream>>>(qkv, mask, part, Ml, T / 2);
    gemm_out_fused<<<(H / 128) * (M / 128), 256, 0, stream>>>(part, Ml, WtO, bout, out, M, H, H);
  } else {
    attn_fwd<false><<<256, 512, 0, stream>>>(qkv, mask, xa, Ml, T);
    gemm_bf16<false><<<(H / 128) * (M / 128), 256, 0, stream>>>(xa, WtO, bout, out, M, H, H);
  }
}

// Round 12
// 172.977 us; speedup vs baseline: 1.0670x; 1.0670x over previous
//
#include <hip/hip_runtime.h>
#include <stdint.h>

typedef unsigned short u16;
typedef unsigned int u32;
typedef short bf16x8 __attribute__((ext_vector_type(8)));
typedef float f32x4 __attribute__((ext_vector_type(4)));

#define MFMA16(a, b, c) __builtin_amdgcn_mfma_f32_16x16x32_bf16((a), (b), (c), 0, 0, 0)

__device__ __forceinline__ u16 f2bf(float f) {
  union { float f; u32 u; } v; v.f = f;
  u32 u = v.u;
  u32 r = (u + 0x7FFFu + ((u >> 16) & 1u)) >> 16;  // RNE
  return (u16)r;
}
__device__ __forceinline__ float bf2f(u16 h) {
  union { u32 u; float f; } v; v.u = ((u32)h) << 16;
  return v.f;
}
// packed f32x2 -> bf16x2 (single HW instruction, RNE)
__device__ __forceinline__ u32 cvtpk_bf16(float lo, float hi) {
  u32 r;
  asm("v_cvt_pk_bf16_f32 %0, %1, %2" : "=v"(r) : "v"(lo), "v"(hi));
  return r;
}

// async global->LDS, 16B per lane. LDS base must be wave-uniform (HW adds lane*16).
__device__ __forceinline__ void gload_lds16(const void* g, void* l) {
  __builtin_amdgcn_global_load_lds(
      (const __attribute__((address_space(1))) unsigned int*)g,
      (__attribute__((address_space(3))) unsigned int*)l,
      16, 0, 0);
}

// ---------------- transpose+convert: src f32 [R][C] -> dst bf16 [C][R] ----------------
__global__ __launch_bounds__(256) void transpose_f32_bf16(
    const float* __restrict__ src, u16* __restrict__ dst, int R, int C) {
  __shared__ u16 t[32][33];
  const int bx = blockIdx.x * 32, by = blockIdx.y * 32;
  const int tx = threadIdx.x & 31, ty = threadIdx.x >> 5;  // 32x8
#pragma unroll
  for (int i = 0; i < 32; i += 8)
    t[ty + i][tx] = f2bf(src[(size_t)(by + ty + i) * C + bx + tx]);
  __syncthreads();
#pragma unroll
  for (int i = 0; i < 32; i += 8)
    dst[(size_t)(bx + ty + i) * R + by + tx] = t[tx][ty + i];
}

// ------- qkv GEMM with fused f32->bf16 on the A path -------
// C[M][N] = cvt(A_f32)[M][K] * Bt[N][K]^T + bias, output bf16.
// A reg-staged (2x float4 -> cvt_pk -> ds_write_b128); B via gload_lds.
__global__ __launch_bounds__(256) void gemm_a32_bf16(
    const float* __restrict__ A, const u16* __restrict__ Bt,
    const float* __restrict__ bias, u16* __restrict__ Cout,
    int M, int N, int K) {
  __shared__ __align__(16) u16 As[128 * 64];
  __shared__ __align__(16) u16 Bs[128 * 64];
  const int tid = threadIdx.x;
  const int lane = tid & 63;
  const int wave = tid >> 6;
  const int nwg = gridDim.x;
  const int id = blockIdx.x;
  const int sw = (id & 7) * (nwg >> 3) + (id >> 3);
  const int nx = N >> 7;
  const int m0 = (sw / nx) * 128;
  const int n0 = (sw % nx) * 128;
  const int wm = (wave >> 1) * 64;
  const int wn = (wave & 1) * 64;

  f32x4 acc[4][4] = {};
  const char* Bbase = (const char*)Bt;

  for (int kt = 0; kt < K; kt += 64) {
    __syncthreads();
    float4 fa[4], fb[4];
#pragma unroll
    for (int i = 0; i < 4; ++i) {
      int flat = wave * 1024 + lane * 16 + i * 4096;
      int row = flat >> 7;
      int colb = flat & 127;
      gload_lds16(Bbase + ((size_t)(n0 + row) * K + kt) * 2 + colb,
                  (char*)Bs + flat);
      const float* ax = A + (size_t)(m0 + row) * K + kt + (colb >> 1);
      fa[i] = *(const float4*)ax;
      fb[i] = *(const float4*)(ax + 4);
    }
#pragma unroll
    for (int i = 0; i < 4; ++i) {
      int flat = wave * 1024 + lane * 16 + i * 4096;
      union { u32 w[4]; bf16x8 v; } o;
      o.w[0] = cvtpk_bf16(fa[i].x, fa[i].y);
      o.w[1] = cvtpk_bf16(fa[i].z, fa[i].w);
      o.w[2] = cvtpk_bf16(fb[i].x, fb[i].y);
      o.w[3] = cvtpk_bf16(fb[i].z, fb[i].w);
      *(bf16x8*)((char*)As + flat) = o.v;
    }
    __syncthreads();
#pragma unroll
    for (int ks = 0; ks < 2; ++ks) {
      const int col = (lane >> 4) * 8 + ks * 32;
      bf16x8 af[4], bfr[4];
#pragma unroll
      for (int mt = 0; mt < 4; ++mt)
        af[mt] = *(const bf16x8*)(As + (wm + mt * 16 + (lane & 15)) * 64 + col);
#pragma unroll
      for (int nt = 0; nt < 4; ++nt)
        bfr[nt] = *(const bf16x8*)(Bs + (wn + nt * 16 + (lane & 15)) * 64 + col);
#pragma unroll
      for (int mt = 0; mt < 4; ++mt)
#pragma unroll
        for (int nt = 0; nt < 4; ++nt)
          acc[mt][nt] = MFMA16(af[mt], bfr[nt], acc[mt][nt]);
    }
  }

  float bv[4];
#pragma unroll
  for (int nt = 0; nt < 4; ++nt)
    bv[nt] = bias[n0 + wn + nt * 16 + (lane & 15)];
#pragma unroll
  for (int mt = 0; mt < 4; ++mt)
#pragma unroll
    for (int nt = 0; nt < 4; ++nt)
#pragma unroll
      for (int r = 0; r < 4; ++r) {
        int m = m0 + wm + mt * 16 + (lane >> 4) * 4 + r;
        int n = n0 + wn + nt * 16 + (lane & 15);
        Cout[(size_t)m * N + n] = f2bf(acc[mt][nt][r] + bv[nt]);
      }
}

// ---------------- GEMM: C[M][N] = A[M][K] * Bt[N][K]^T + bias ----------------
// 1D grid + bijective XCD swizzle (nwg % 8 == 0 for all our launches).
template <bool OUT_BF16>
__global__ __launch_bounds__(256) void gemm_bf16(
    const u16* __restrict__ A, const u16* __restrict__ Bt,
    const float* __restrict__ bias, void* __restrict__ Cout,
    int M, int N, int K) {
  __shared__ __align__(16) u16 As[128 * 64];
  __shared__ __align__(16) u16 Bs[128 * 64];
  const int tid = threadIdx.x;
  const int lane = tid & 63;
  const int wave = tid >> 6;
  const int nwg = gridDim.x;
  const int id = blockIdx.x;
  const int sw = (id & 7) * (nwg >> 3) + (id >> 3);
  const int nx = N >> 7;
  const int m0 = (sw / nx) * 128;
  const int n0 = (sw % nx) * 128;
  const int wm = (wave >> 1) * 64;
  const int wn = (wave & 1) * 64;

  f32x4 acc[4][4] = {};

  const char* Abase = (const char*)A;
  const char* Bbase = (const char*)Bt;

  for (int kt = 0; kt < K; kt += 64) {
    __syncthreads();
#pragma unroll
    for (int i = 0; i < 4; ++i) {
      int flat = wave * 1024 + lane * 16 + i * 4096;
      int row = flat >> 7;
      int colb = flat & 127;
      gload_lds16(Abase + ((size_t)(m0 + row) * K + kt) * 2 + colb,
                  (char*)As + flat);
      gload_lds16(Bbase + ((size_t)(n0 + row) * K + kt) * 2 + colb,
                  (char*)Bs + flat);
    }
    __syncthreads();
#pragma unroll
    for (int ks = 0; ks < 2; ++ks) {
      const int col = (lane >> 4) * 8 + ks * 32;
      bf16x8 af[4], bfr[4];
#pragma unroll
      for (int mt = 0; mt < 4; ++mt)
        af[mt] = *(const bf16x8*)(As + (wm + mt * 16 + (lane & 15)) * 64 + col);
#pragma unroll
      for (int nt = 0; nt < 4; ++nt)
        bfr[nt] = *(const bf16x8*)(Bs + (wn + nt * 16 + (lane & 15)) * 64 + col);
#pragma unroll
      for (int mt = 0; mt < 4; ++mt)
#pragma unroll
        for (int nt = 0; nt < 4; ++nt)
          acc[mt][nt] = MFMA16(af[mt], bfr[nt], acc[mt][nt]);
    }
  }

  float bv[4];
#pragma unroll
  for (int nt = 0; nt < 4; ++nt)
    bv[nt] = bias[n0 + wn + nt * 16 + (lane & 15)];
#pragma unroll
  for (int mt = 0; mt < 4; ++mt)
#pragma unroll
    for (int nt = 0; nt < 4; ++nt)
#pragma unroll
      for (int r = 0; r < 4; ++r) {
        int m = m0 + wm + mt * 16 + (lane >> 4) * 4 + r;
        int n = n0 + wn + nt * 16 + (lane & 15);
        float v = acc[mt][nt][r] + bv[nt];
        if (OUT_BF16)
          ((u16*)Cout)[(size_t)m * N + n] = f2bf(v);
        else
          ((float*)Cout)[(size_t)m * N + n] = v;
      }
}

// ---------------- flash attention (v11: XCD-affinity grid, 128-key stages) ----
// 1D grid; id = (hz&7) + 8*(q + 8*(hz>>3)) -> the 8 q-blocks of one (h,z)
// share one XCD's L2 for their K/V panel (FETCH 73.8 -> 16.5 MB, round 11).
// S^T = mfma(K,Q), m=0 softmax, mask via zero-V + MFMA row-sum w/ LDS LUT,
// 128-key double-buffered stages. NOTE: no min-waves clause (round-5 spills).
#define T_SEQ 2048
#define ROWQKV 3072
#define SCL 0.180336880f  /* (1/sqrt(64)) * log2(e) */

template <bool SPLIT>
__global__ __launch_bounds__(512) void attn_fwd(
    const u16* __restrict__ qkv, const int* __restrict__ mask,
    u16* __restrict__ outp, float* __restrict__ Ml, int nk) {
  __shared__ __align__(16) u16 Ks[2][2][64 * 64];  // [buf][half][key][dk], swz s=row&7
  __shared__ __align__(16) u16 Vt[2][2][64 * 64];  // [buf][half][d][key], swz row^(row>>3)
  __shared__ u32 mkb[64];                          // key-mask bitset (nk bits used)
  __shared__ __align__(16) u32 lut[256 * 4];       // byte -> 8 x bf16 {0,1}

  const int tid = threadIdx.x;
  const int lane = tid & 63;
  const int wave = tid >> 6;
  const int r15 = lane & 15;
  const int g = lane >> 4;
  const bool hi = (g >> 1) != 0;
  const int id = blockIdx.x;
  const int hz = ((id >> 6) << 3) | (id & 7);
  const int qb = (id >> 3) & 7;
  const int h = SPLIT ? (hz >> 2) : (hz >> 1);
  const int z = SPLIT ? (hz & 3) : (hz & 1);
  const int split = SPLIT ? (z >> 1) : 0;
  const int b = SPLIT ? (z & 1) : z;
  const int s0 = split * nk;
  const int q0 = qb * 256 + wave * 32;
  const size_t rowb = (size_t)b * T_SEQ;

  for (int i = wave; i < (nk >> 6); i += 8) {
    unsigned long long bm =
        __ballot(mask[b * T_SEQ + s0 + i * 64 + lane] != 0);
    if (lane == 0) {
      mkb[2 * i] = (u32)bm;
      mkb[2 * i + 1] = (u32)(bm >> 32);
    }
  }
  for (int i = tid; i < 256; i += 512) {
    union { u32 w[4]; bf16x8 v; } e;
#pragma unroll
    for (int j = 0; j < 4; ++j)
      e.w[j] = (((i >> (2 * j)) & 1) ? 0x3F80u : 0u) |
               (((i >> (2 * j + 1)) & 1) ? 0x3F800000u : 0u);
    *(bf16x8*)((char*)lut + i * 16) = e.v;
  }

  bf16x8 aq[2][2];
#pragma unroll
  for (int mt = 0; mt < 2; ++mt)
#pragma unroll
    for (int ks = 0; ks < 2; ++ks) {
      bf16x8 t = *(const bf16x8*)(qkv +
          (rowb + q0 + mt * 16 + r15) * ROWQKV + h * 64 + g * 8 + ks * 32);
#pragma unroll
      for (int j = 0; j < 8; ++j) t[j] = (short)f2bf(bf2f((u16)t[j]) * SCL);
      aq[mt][ks] = t;
    }

  f32x4 accO[2][4] = {};
  f32x4 ssum[2] = {};
  bf16x8 vr0, vr1;

#define ISSUE_K2(ktile, buf)                                                   \
  {                                                                            \
    int L = wave * 1024 + lane * 16;                                           \
    int row = L >> 7;                                                          \
    int cb = L & 127;                                                          \
    int scb = cb ^ ((row & 7) << 4);                                           \
    gload_lds16((const char*)qkv +                                             \
                    ((rowb + (ktile) + row) * ROWQKV + 1024 + h * 64) * 2 + scb, \
                (char*)&Ks[buf][0][0] + wave * 1024);                          \
    gload_lds16((const char*)qkv +                                             \
                    ((rowb + (ktile) + 64 + row) * ROWQKV + 1024 + h * 64) * 2 + scb, \
                (char*)&Ks[buf][1][0] + wave * 1024);                          \
  }

#define LOAD_V2(ktile)                                                         \
  {                                                                            \
    vr0 = *(const bf16x8*)(qkv + (rowb + (ktile) + (tid >> 3)) * ROWQKV +      \
                           2048 + h * 64 + (tid & 7) * 8);                     \
    vr1 = *(const bf16x8*)(qkv + (rowb + (ktile) + 64 + (tid >> 3)) * ROWQKV + \
                           2048 + h * 64 + (tid & 7) * 8);                     \
  }

#define WRITE_V2(buf, t4)                                                      \
  {                                                                            \
    int key = tid >> 3;                                                        \
    u32 w0 = mkb[(t4) + (key >> 5)];                                           \
    if (!((w0 >> (key & 31)) & 1u)) {                                          \
      bf16x8 zz = {};                                                          \
      vr0 = zz;                                                                \
    }                                                                          \
    u32 w1 = mkb[(t4) + 2 + (key >> 5)];                                       \
    if (!((w1 >> (key & 31)) & 1u)) {                                          \
      bf16x8 zz = {};                                                          \
      vr1 = zz;                                                                \
    }                                                                          \
    _Pragma("unroll") for (int j = 0; j < 8; ++j) {                            \
      int row = (tid & 7) * 8 + j;                                             \
      int sv = ((row ^ (row >> 3)) & 7) << 4;                                  \
      *(u16*)((char*)&Vt[buf][0][0] + row * 128 + ((key * 2) ^ sv)) =          \
          (u16)vr0[j];                                                         \
      *(u16*)((char*)&Vt[buf][1][0] + row * 128 + ((key * 2) ^ sv)) =          \
          (u16)vr1[j];                                                         \
    }                                                                          \
  }

#define COMPUTE_HALF(H, bw)                                                    \
  {                                                                            \
    f32x4 s[2][4] = {};                                                        \
    _Pragma("unroll") for (int ks = 0; ks < 2; ++ks) {                         \
      bf16x8 bk[4];                                                            \
      _Pragma("unroll") for (int nt = 0; nt < 4; ++nt) {                       \
        int row = nt * 16 + r15;                                               \
        int cb = (g * 8 + ks * 32) * 2;                                        \
        bk[nt] = *(const bf16x8*)((const char*)&Ks[cur][H][0] + row * 128 +    \
                                  (cb ^ ((row & 7) << 4)));                    \
      }                                                                        \
      _Pragma("unroll") for (int mt = 0; mt < 2; ++mt)                         \
        _Pragma("unroll") for (int nt = 0; nt < 4; ++nt)                       \
          s[mt][nt] = MFMA16(bk[nt], aq[mt][ks], s[mt][nt]);                   \
    }                                                                          \
    u32 pk[2][4][2];                                                           \
    _Pragma("unroll") for (int mt = 0; mt < 2; ++mt)                           \
      _Pragma("unroll") for (int nt = 0; nt < 4; ++nt) {                       \
        float e0 = exp2f(s[mt][nt][0]);                                        \
        float e1 = exp2f(s[mt][nt][1]);                                        \
        float e2 = exp2f(s[mt][nt][2]);                                        \
        float e3 = exp2f(s[mt][nt][3]);                                        \
        pk[mt][nt][0] = cvtpk_bf16(e0, e1);                                    \
        pk[mt][nt][1] = cvtpk_bf16(e2, e3);                                    \
      }                                                                        \
    const int srcA = ((g & 1) << 5) + r15;                                     \
    const int srcB = srcA + 16;                                                \
    __builtin_amdgcn_s_setprio(1);                                             \
    _Pragma("unroll") for (int ks = 0; ks < 2; ++ks) {                         \
      const int col = g * 8 + ks * 32;                                         \
      bf16x8 bv[4];                                                            \
      _Pragma("unroll") for (int nt = 0; nt < 4; ++nt) {                       \
        int row = nt * 16 + r15;                                               \
        int sv = ((row ^ (row >> 3)) & 7) << 4;                                \
        bv[nt] = *(const bf16x8*)((const char*)&Vt[cur][H][0] + row * 128 +    \
                                  ((col * 2) ^ sv));                           \
      }                                                                        \
      u32 wb = mkb[(bw) + ks];                                                 \
      u32 lb = (wb >> (g * 8)) & 0xFFu;                                        \
      bf16x8 mf = *(const bf16x8*)((const char*)lut + lb * 16);                \
      _Pragma("unroll") for (int mt = 0; mt < 2; ++mt) {                       \
        u32 a0l = (u32)__shfl((int)pk[mt][2 * ks][0], srcA);                   \
        u32 a0h = (u32)__shfl((int)pk[mt][2 * ks + 1][0], srcA);               \
        u32 a1l = (u32)__shfl((int)pk[mt][2 * ks][1], srcA);                   \
        u32 a1h = (u32)__shfl((int)pk[mt][2 * ks + 1][1], srcA);               \
        u32 b0l = (u32)__shfl((int)pk[mt][2 * ks][0], srcB);                   \
        u32 b0h = (u32)__shfl((int)pk[mt][2 * ks + 1][0], srcB);               \
        u32 b1l = (u32)__shfl((int)pk[mt][2 * ks][1], srcB);                   \
        u32 b1h = (u32)__shfl((int)pk[mt][2 * ks + 1][1], srcB);               \
        union { u32 w[4]; bf16x8 v; } ap;                                      \
        ap.w[0] = hi ? a0h : a0l;                                              \
        ap.w[1] = hi ? a1h : a1l;                                              \
        ap.w[2] = hi ? b0h : b0l;                                              \
        ap.w[3] = hi ? b1h : b1l;                                              \
        _Pragma("unroll") for (int nt = 0; nt < 4; ++nt)                       \
          accO[mt][nt] = MFMA16(ap.v, bv[nt], accO[mt][nt]);                   \
        ssum[mt] = MFMA16(ap.v, mf, ssum[mt]);                                 \
      }                                                                        \
    }                                                                          \
    __builtin_amdgcn_s_setprio(0);                                             \
  }

  // prologue
  ISSUE_K2(s0, 0);
  LOAD_V2(s0);
  __syncthreads();
  WRITE_V2(0, 0);
  asm volatile("s_waitcnt lgkmcnt(0)" ::: "memory");
  __builtin_amdgcn_sched_barrier(0);
  __builtin_amdgcn_s_barrier();
  __builtin_amdgcn_sched_barrier(0);

  const int nt2 = nk >> 7;  // 128-key stages
  int cur = 0;
  for (int t = 0; t < nt2; ++t) {
    const int kt = s0 + t * 128;
    if (t < nt2 - 1) {
      ISSUE_K2(kt + 128, cur ^ 1);
      LOAD_V2(kt + 128);
    }

    COMPUTE_HALF(0, 4 * t);
    COMPUTE_HALF(1, 4 * t + 2);

    if (t < nt2 - 1) {
      asm volatile("s_waitcnt vmcnt(0)" ::: "memory");
      WRITE_V2(cur ^ 1, 4 * (t + 1));
      asm volatile("s_waitcnt lgkmcnt(0)" ::: "memory");
      __builtin_amdgcn_sched_barrier(0);
      __builtin_amdgcn_s_barrier();
      __builtin_amdgcn_sched_barrier(0);
      cur ^= 1;
    }
  }

  if (SPLIT) {
    u16* po = outp + (size_t)split * T_SEQ * 2 * 1024;
#pragma unroll
    for (int mt = 0; mt < 2; ++mt) {
#pragma unroll
      for (int r = 0; r < 4; ++r) {
        int q = q0 + mt * 16 + g * 4 + r;
#pragma unroll
        for (int nt = 0; nt < 4; ++nt)
          po[(rowb + q) * 1024 + h * 64 + nt * 16 + r15] = f2bf(accO[mt][nt][r]);
      }
      if (r15 == 0) {
        int idx = ((split * 2 + b) * 16 + h) * T_SEQ + q0 + mt * 16 + g * 4;
        *(f32x4*)(Ml + idx) = ssum[mt];
      }
    }
  } else {
#pragma unroll
    for (int mt = 0; mt < 2; ++mt)
#pragma unroll
      for (int r = 0; r < 4; ++r) {
        float inv = 1.f / ssum[mt][r];
        int q = q0 + mt * 16 + g * 4 + r;
#pragma unroll
        for (int nt = 0; nt < 4; ++nt)
          outp[(rowb + q) * 1024 + h * 64 + nt * 16 + r15] =
              f2bf(accO[mt][nt][r] * inv);
      }
  }
#undef ISSUE_K2
#undef LOAD_V2
#undef WRITE_V2
#undef COMPUTE_HALF
}

// ---------------- combine two KV-splits (m=0: just l0+l1) ----------------
__global__ __launch_bounds__(256) void attn_combine(
    const u16* __restrict__ part, const float* __restrict__ Ml,
    u16* __restrict__ att) {
  int idx = blockIdx.x * 256 + threadIdx.x;  // (B*T)*(H/8) = 524288
  int row = idx >> 7;                        // b*2048 + q
  int c8 = idx & 127;
  int col = c8 * 8;
  int h = c8 >> 3;
  int b = row >> 11, q = row & 2047;
  float l0 = Ml[(b * 16 + h) * T_SEQ + q];
  float l1 = Ml[((2 + b) * 16 + h) * T_SEQ + q];
  float inv = 1.f / (l0 + l1);
  bf16x8 o0 = *(const bf16x8*)(part + (size_t)row * 1024 + col);
  bf16x8 o1 = *(const bf16x8*)(part + (size_t)T_SEQ * 2 * 1024 +
                               (size_t)row * 1024 + col);
  bf16x8 o;
#pragma unroll
  for (int j = 0; j < 8; ++j)
    o[j] = (short)f2bf((bf2f((u16)o0[j]) + bf2f((u16)o1[j])) * inv);
  *(bf16x8*)(att + (size_t)row * 1024 + col) = o;
}

// ---------------- launch ----------------
extern "C" void kernel_launch(void* const* d_in, const int* in_sizes, int n_in,
                              void* d_out, int out_size, void* d_ws, size_t ws_size,
                              hipStream_t stream) {
  const float* x = (const float*)d_in[0];     // [2,2048,1024] f32
  const int* mask = (const int*)d_in[1];      // [2,1,1,2048] int32
  const float* Wqkv = (const float*)d_in[2];  // [1024,3072] f32
  const float* bqkv = (const float*)d_in[3];  // [3072] f32
  const float* Wout = (const float*)d_in[4];  // [1024,1024] f32
  const float* bout = (const float*)d_in[5];  // [1024] f32
  float* out = (float*)d_out;                 // [2,2048,1024] f32

  const int B = 2, T = 2048, H = 1024, M = B * T;

  u16* qkv = (u16*)d_ws;                       // M*3H
  u16* att = qkv + (size_t)M * 3 * H;          // M*H
  u16* WtQ = att + (size_t)M * H;              // 3H*H
  u16* WtO = WtQ + (size_t)3 * H * H;          // H*H
  u16* part = WtO + (size_t)H * H;             // 2 * M*H  (split partials)
  float* Ml = (float*)(part + (size_t)2 * M * H);  // 2*65536 floats (l only)

  const size_t need = ((size_t)M * 3 * H + (size_t)M * H + (size_t)3 * H * H +
                       (size_t)H * H + (size_t)2 * M * H) * 2 +
                      (size_t)2 * 131072 * 4;
  const bool split = ws_size >= need;

  transpose_f32_bf16<<<dim3(3 * H / 32, H / 32), 256, 0, stream>>>(Wqkv, WtQ, H, 3 * H);
  transpose_f32_bf16<<<dim3(H / 32, H / 32), 256, 0, stream>>>(Wout, WtO, H, H);
  gemm_a32_bf16<<<(3 * H / 128) * (M / 128), 256, 0, stream>>>(x, WtQ, bqkv, qkv, M, 3 * H, H);
  if (split) {
    attn_fwd<true><<<512, 512, 0, stream>>>(qkv, mask, part, Ml, T / 2);
    attn_combine<<<(M * H / 8 + 255) / 256, 256, 0, stream>>>(part, Ml, att);
  } else {
    attn_fwd<false><<<256, 512, 0, stream>>>(qkv, mask, att, Ml, T);
  }
  gemm_bf16<false><<<(H / 128) * (M / 128), 256, 0, stream>>>(att, WtO, bout, out, M, H, H);
}

// Round 13
// 166.498 us; speedup vs baseline: 1.1085x; 1.0389x over previous
//
#include <hip/hip_runtime.h>
#include <stdint.h>

typedef unsigned short u16;
typedef unsigned int u32;
typedef short bf16x8 __attribute__((ext_vector_type(8)));
typedef float f32x4 __attribute__((ext_vector_type(4)));

#define MFMA16(a, b, c) __builtin_amdgcn_mfma_f32_16x16x32_bf16((a), (b), (c), 0, 0, 0)

__device__ __forceinline__ u16 f2bf(float f) {
  union { float f; u32 u; } v; v.f = f;
  u32 u = v.u;
  u32 r = (u + 0x7FFFu + ((u >> 16) & 1u)) >> 16;  // RNE
  return (u16)r;
}
__device__ __forceinline__ float bf2f(u16 h) {
  union { u32 u; float f; } v; v.u = ((u32)h) << 16;
  return v.f;
}
// packed f32x2 -> bf16x2 (single HW instruction, RNE)
__device__ __forceinline__ u32 cvtpk_bf16(float lo, float hi) {
  u32 r;
  asm("v_cvt_pk_bf16_f32 %0, %1, %2" : "=v"(r) : "v"(lo), "v"(hi));
  return r;
}

// async global->LDS, 16B per lane. LDS base must be wave-uniform (HW adds lane*16).
__device__ __forceinline__ void gload_lds16(const void* g, void* l) {
  __builtin_amdgcn_global_load_lds(
      (const __attribute__((address_space(1))) unsigned int*)g,
      (__attribute__((address_space(3))) unsigned int*)l,
      16, 0, 0);
}

// ---------------- transpose+convert: src f32 [R][C] -> dst bf16 [C][R] ----------------
__global__ __launch_bounds__(256) void transpose_f32_bf16(
    const float* __restrict__ src, u16* __restrict__ dst, int R, int C) {
  __shared__ u16 t[32][33];
  const int bx = blockIdx.x * 32, by = blockIdx.y * 32;
  const int tx = threadIdx.x & 31, ty = threadIdx.x >> 5;  // 32x8
#pragma unroll
  for (int i = 0; i < 32; i += 8)
    t[ty + i][tx] = f2bf(src[(size_t)(by + ty + i) * C + bx + tx]);
  __syncthreads();
#pragma unroll
  for (int i = 0; i < 32; i += 8)
    dst[(size_t)(bx + ty + i) * R + by + tx] = t[tx][ty + i];
}

// ------- qkv GEMM with fused f32->bf16 on the A path -------
__global__ __launch_bounds__(256) void gemm_a32_bf16(
    const float* __restrict__ A, const u16* __restrict__ Bt,
    const float* __restrict__ bias, u16* __restrict__ Cout,
    int M, int N, int K) {
  __shared__ __align__(16) u16 As[128 * 64];
  __shared__ __align__(16) u16 Bs[128 * 64];
  const int tid = threadIdx.x;
  const int lane = tid & 63;
  const int wave = tid >> 6;
  const int nwg = gridDim.x;
  const int id = blockIdx.x;
  const int sw = (id & 7) * (nwg >> 3) + (id >> 3);
  const int nx = N >> 7;
  const int m0 = (sw / nx) * 128;
  const int n0 = (sw % nx) * 128;
  const int wm = (wave >> 1) * 64;
  const int wn = (wave & 1) * 64;

  f32x4 acc[4][4] = {};
  const char* Bbase = (const char*)Bt;

  for (int kt = 0; kt < K; kt += 64) {
    __syncthreads();
    float4 fa[4], fb[4];
#pragma unroll
    for (int i = 0; i < 4; ++i) {
      int flat = wave * 1024 + lane * 16 + i * 4096;
      int row = flat >> 7;
      int colb = flat & 127;
      gload_lds16(Bbase + ((size_t)(n0 + row) * K + kt) * 2 + colb,
                  (char*)Bs + flat);
      const float* ax = A + (size_t)(m0 + row) * K + kt + (colb >> 1);
      fa[i] = *(const float4*)ax;
      fb[i] = *(const float4*)(ax + 4);
    }
#pragma unroll
    for (int i = 0; i < 4; ++i) {
      int flat = wave * 1024 + lane * 16 + i * 4096;
      union { u32 w[4]; bf16x8 v; } o;
      o.w[0] = cvtpk_bf16(fa[i].x, fa[i].y);
      o.w[1] = cvtpk_bf16(fa[i].z, fa[i].w);
      o.w[2] = cvtpk_bf16(fb[i].x, fb[i].y);
      o.w[3] = cvtpk_bf16(fb[i].z, fb[i].w);
      *(bf16x8*)((char*)As + flat) = o.v;
    }
    __syncthreads();
#pragma unroll
    for (int ks = 0; ks < 2; ++ks) {
      const int col = (lane >> 4) * 8 + ks * 32;
      bf16x8 af[4], bfr[4];
#pragma unroll
      for (int mt = 0; mt < 4; ++mt)
        af[mt] = *(const bf16x8*)(As + (wm + mt * 16 + (lane & 15)) * 64 + col);
#pragma unroll
      for (int nt = 0; nt < 4; ++nt)
        bfr[nt] = *(const bf16x8*)(Bs + (wn + nt * 16 + (lane & 15)) * 64 + col);
#pragma unroll
      for (int mt = 0; mt < 4; ++mt)
#pragma unroll
        for (int nt = 0; nt < 4; ++nt)
          acc[mt][nt] = MFMA16(af[mt], bfr[nt], acc[mt][nt]);
    }
  }

  float bv[4];
#pragma unroll
  for (int nt = 0; nt < 4; ++nt)
    bv[nt] = bias[n0 + wn + nt * 16 + (lane & 15)];
#pragma unroll
  for (int mt = 0; mt < 4; ++mt)
#pragma unroll
    for (int nt = 0; nt < 4; ++nt)
#pragma unroll
      for (int r = 0; r < 4; ++r) {
        int m = m0 + wm + mt * 16 + (lane >> 4) * 4 + r;
        int n = n0 + wn + nt * 16 + (lane & 15);
        Cout[(size_t)m * N + n] = f2bf(acc[mt][nt][r] + bv[nt]);
      }
}

// ---------------- GEMM: C[M][N] = A[M][K] * Bt[N][K]^T + bias ----------------
template <bool OUT_BF16>
__global__ __launch_bounds__(256) void gemm_bf16(
    const u16* __restrict__ A, const u16* __restrict__ Bt,
    const float* __restrict__ bias, void* __restrict__ Cout,
    int M, int N, int K) {
  __shared__ __align__(16) u16 As[128 * 64];
  __shared__ __align__(16) u16 Bs[128 * 64];
  const int tid = threadIdx.x;
  const int lane = tid & 63;
  const int wave = tid >> 6;
  const int nwg = gridDim.x;
  const int id = blockIdx.x;
  const int sw = (id & 7) * (nwg >> 3) + (id >> 3);
  const int nx = N >> 7;
  const int m0 = (sw / nx) * 128;
  const int n0 = (sw % nx) * 128;
  const int wm = (wave >> 1) * 64;
  const int wn = (wave & 1) * 64;

  f32x4 acc[4][4] = {};

  const char* Abase = (const char*)A;
  const char* Bbase = (const char*)Bt;

  for (int kt = 0; kt < K; kt += 64) {
    __syncthreads();
#pragma unroll
    for (int i = 0; i < 4; ++i) {
      int flat = wave * 1024 + lane * 16 + i * 4096;
      int row = flat >> 7;
      int colb = flat & 127;
      gload_lds16(Abase + ((size_t)(m0 + row) * K + kt) * 2 + colb,
                  (char*)As + flat);
      gload_lds16(Bbase + ((size_t)(n0 + row) * K + kt) * 2 + colb,
                  (char*)Bs + flat);
    }
    __syncthreads();
#pragma unroll
    for (int ks = 0; ks < 2; ++ks) {
      const int col = (lane >> 4) * 8 + ks * 32;
      bf16x8 af[4], bfr[4];
#pragma unroll
      for (int mt = 0; mt < 4; ++mt)
        af[mt] = *(const bf16x8*)(As + (wm + mt * 16 + (lane & 15)) * 64 + col);
#pragma unroll
      for (int nt = 0; nt < 4; ++nt)
        bfr[nt] = *(const bf16x8*)(Bs + (wn + nt * 16 + (lane & 15)) * 64 + col);
#pragma unroll
      for (int mt = 0; mt < 4; ++mt)
#pragma unroll
        for (int nt = 0; nt < 4; ++nt)
          acc[mt][nt] = MFMA16(af[mt], bfr[nt], acc[mt][nt]);
    }
  }

  float bv[4];
#pragma unroll
  for (int nt = 0; nt < 4; ++nt)
    bv[nt] = bias[n0 + wn + nt * 16 + (lane & 15)];
#pragma unroll
  for (int mt = 0; mt < 4; ++mt)
#pragma unroll
    for (int nt = 0; nt < 4; ++nt)
#pragma unroll
      for (int r = 0; r < 4; ++r) {
        int m = m0 + wm + mt * 16 + (lane >> 4) * 4 + r;
        int n = n0 + wn + nt * 16 + (lane & 15);
        float v = acc[mt][nt][r] + bv[nt];
        if (OUT_BF16)
          ((u16*)Cout)[(size_t)m * N + n] = f2bf(v);
        else
          ((float*)Cout)[(size_t)m * N + n] = v;
      }
}

// ---------------- flash attention (v12: permuted-K staging, zero-shuffle PV) ----
// K rows staged permuted by pi(16nt+4g+r) = 32(nt&1)+8g+4(nt>>1)+r. Then lane's
// QK^T outputs s[nt][r] hold exactly the keys its PV A-fragment needs:
// ap(ks) = [pk[ks][0], pk[ks][1], pk[2+ks][0], pk[2+ks][1]] -- ZERO shuffles
// (was 64 ds_bpermute + 32 selects per stage). pi cancels in the PV k-dim, so
// V / mask-frag / ssum stay unpermuted; m=0 softmax is permutation-invariant.
// XCD-affinity grid (FETCH 16.5 MB), 128-key double-buffered stages.
// NOTE: no min-waves clause (round-5 spills).
#define T_SEQ 2048
#define ROWQKV 3072
#define SCL 0.180336880f  /* (1/sqrt(64)) * log2(e) */

template <bool SPLIT>
__global__ __launch_bounds__(512) void attn_fwd(
    const u16* __restrict__ qkv, const int* __restrict__ mask,
    u16* __restrict__ outp, float* __restrict__ Ml, int nk) {
  __shared__ __align__(16) u16 Ks[2][2][64 * 64];  // [buf][half][storerow][dk], swz s=row&7
  __shared__ __align__(16) u16 Vt[2][2][64 * 64];  // [buf][half][d][key], swz row^(row>>3)
  __shared__ u32 mkb[64];                          // key-mask bitset (nk bits used)
  __shared__ __align__(16) u32 lut[256 * 4];       // byte -> 8 x bf16 {0,1}

  const int tid = threadIdx.x;
  const int lane = tid & 63;
  const int wave = tid >> 6;
  const int r15 = lane & 15;
  const int g = lane >> 4;
  const int id = blockIdx.x;
  const int hz = ((id >> 6) << 3) | (id & 7);
  const int qb = (id >> 3) & 7;
  const int h = SPLIT ? (hz >> 2) : (hz >> 1);
  const int z = SPLIT ? (hz & 3) : (hz & 1);
  const int split = SPLIT ? (z >> 1) : 0;
  const int b = SPLIT ? (z & 1) : z;
  const int s0 = split * nk;
  const int q0 = qb * 256 + wave * 32;
  const size_t rowb = (size_t)b * T_SEQ;

  for (int i = wave; i < (nk >> 6); i += 8) {
    unsigned long long bm =
        __ballot(mask[b * T_SEQ + s0 + i * 64 + lane] != 0);
    if (lane == 0) {
      mkb[2 * i] = (u32)bm;
      mkb[2 * i + 1] = (u32)(bm >> 32);
    }
  }
  for (int i = tid; i < 256; i += 512) {
    union { u32 w[4]; bf16x8 v; } e;
#pragma unroll
    for (int j = 0; j < 4; ++j)
      e.w[j] = (((i >> (2 * j)) & 1) ? 0x3F80u : 0u) |
               (((i >> (2 * j + 1)) & 1) ? 0x3F800000u : 0u);
    *(bf16x8*)((char*)lut + i * 16) = e.v;
  }

  bf16x8 aq[2][2];
#pragma unroll
  for (int mt = 0; mt < 2; ++mt)
#pragma unroll
    for (int ks = 0; ks < 2; ++ks) {
      bf16x8 t = *(const bf16x8*)(qkv +
          (rowb + q0 + mt * 16 + r15) * ROWQKV + h * 64 + g * 8 + ks * 32);
#pragma unroll
      for (int j = 0; j < 8; ++j) t[j] = (short)f2bf(bf2f((u16)t[j]) * SCL);
      aq[mt][ks] = t;
    }

  f32x4 accO[2][4] = {};
  f32x4 ssum[2] = {};
  bf16x8 vr0, vr1;

// stage 128 keys of K (permuted rows) into both halves of buf
#define ISSUE_K2(ktile, buf)                                                   \
  {                                                                            \
    int L = wave * 1024 + lane * 16;                                           \
    int row = L >> 7; /* storage row 0..63 */                                  \
    int cb = L & 127;                                                          \
    int scb = cb ^ ((row & 7) << 4);                                           \
    int prow = ((row >> 4) & 1) * 32 + ((row >> 2) & 3) * 8 +                  \
               (row >> 5) * 4 + (row & 3); /* pi(row): actual key offset */    \
    gload_lds16((const char*)qkv +                                             \
                    ((rowb + (ktile) + prow) * ROWQKV + 1024 + h * 64) * 2 + scb, \
                (char*)&Ks[buf][0][0] + wave * 1024);                          \
    gload_lds16((const char*)qkv +                                             \
                    ((rowb + (ktile) + 64 + prow) * ROWQKV + 1024 + h * 64) * 2 + scb, \
                (char*)&Ks[buf][1][0] + wave * 1024);                          \
  }

#define LOAD_V2(ktile)                                                         \
  {                                                                            \
    vr0 = *(const bf16x8*)(qkv + (rowb + (ktile) + (tid >> 3)) * ROWQKV +      \
                           2048 + h * 64 + (tid & 7) * 8);                     \
    vr1 = *(const bf16x8*)(qkv + (rowb + (ktile) + 64 + (tid >> 3)) * ROWQKV + \
                           2048 + h * 64 + (tid & 7) * 8);                     \
  }

#define WRITE_V2(buf, t4)                                                      \
  {                                                                            \
    int key = tid >> 3;                                                        \
    u32 w0 = mkb[(t4) + (key >> 5)];                                           \
    if (!((w0 >> (key & 31)) & 1u)) {                                          \
      bf16x8 zz = {};                                                          \
      vr0 = zz;                                                                \
    }                                                                          \
    u32 w1 = mkb[(t4) + 2 + (key >> 5)];                                       \
    if (!((w1 >> (key & 31)) & 1u)) {                                          \
      bf16x8 zz = {};                                                          \
      vr1 = zz;                                                                \
    }                                                                          \
    _Pragma("unroll") for (int j = 0; j < 8; ++j) {                            \
      int row = (tid & 7) * 8 + j;                                             \
      int sv = ((row ^ (row >> 3)) & 7) << 4;                                  \
      *(u16*)((char*)&Vt[buf][0][0] + row * 128 + ((key * 2) ^ sv)) =          \
          (u16)vr0[j];                                                         \
      *(u16*)((char*)&Vt[buf][1][0] + row * 128 + ((key * 2) ^ sv)) =          \
          (u16)vr1[j];                                                         \
    }                                                                          \
  }

#define COMPUTE_HALF(H, bw)                                                    \
  {                                                                            \
    f32x4 s[2][4] = {};                                                        \
    _Pragma("unroll") for (int ks = 0; ks < 2; ++ks) {                         \
      bf16x8 bk[4];                                                            \
      _Pragma("unroll") for (int nt = 0; nt < 4; ++nt) {                       \
        int row = nt * 16 + r15;                                               \
        int cb = (g * 8 + ks * 32) * 2;                                        \
        bk[nt] = *(const bf16x8*)((const char*)&Ks[cur][H][0] + row * 128 +    \
                                  (cb ^ ((row & 7) << 4)));                    \
      }                                                                        \
      _Pragma("unroll") for (int mt = 0; mt < 2; ++mt)                         \
        _Pragma("unroll") for (int nt = 0; nt < 4; ++nt)                       \
          s[mt][nt] = MFMA16(bk[nt], aq[mt][ks], s[mt][nt]);                   \
    }                                                                          \
    u32 pk[2][4][2];                                                           \
    _Pragma("unroll") for (int mt = 0; mt < 2; ++mt)                           \
      _Pragma("unroll") for (int nt = 0; nt < 4; ++nt) {                       \
        float e0 = exp2f(s[mt][nt][0]);                                        \
        float e1 = exp2f(s[mt][nt][1]);                                        \
        float e2 = exp2f(s[mt][nt][2]);                                        \
        float e3 = exp2f(s[mt][nt][3]);                                        \
        pk[mt][nt][0] = cvtpk_bf16(e0, e1);                                    \
        pk[mt][nt][1] = cvtpk_bf16(e2, e3);                                    \
      }                                                                        \
    __builtin_amdgcn_s_setprio(1);                                             \
    _Pragma("unroll") for (int ks = 0; ks < 2; ++ks) {                         \
      const int col = g * 8 + ks * 32;                                         \
      bf16x8 bv[4];                                                            \
      _Pragma("unroll") for (int nt = 0; nt < 4; ++nt) {                       \
        int row = nt * 16 + r15;                                               \
        int sv = ((row ^ (row >> 3)) & 7) << 4;                                \
        bv[nt] = *(const bf16x8*)((const char*)&Vt[cur][H][0] + row * 128 +    \
                                  ((col * 2) ^ sv));                           \
      }                                                                        \
      u32 wb = mkb[(bw) + ks];                                                 \
      u32 lb = (wb >> (g * 8)) & 0xFFu;                                        \
      bf16x8 mf = *(const bf16x8*)((const char*)lut + lb * 16);                \
      _Pragma("unroll") for (int mt = 0; mt < 2; ++mt) {                       \
        union { u32 w[4]; bf16x8 v; } ap; /* zero-shuffle A-frag via pi */     \
        ap.w[0] = pk[mt][ks][0];                                               \
        ap.w[1] = pk[mt][ks][1];                                               \
        ap.w[2] = pk[mt][2 + ks][0];                                           \
        ap.w[3] = pk[mt][2 + ks][1];                                           \
        _Pragma("unroll") for (int nt = 0; nt < 4; ++nt)                       \
          accO[mt][nt] = MFMA16(ap.v, bv[nt], accO[mt][nt]);                   \
        ssum[mt] = MFMA16(ap.v, mf, ssum[mt]);                                 \
      }                                                                        \
    }                                                                          \
    __builtin_amdgcn_s_setprio(0);                                             \
  }

  // prologue
  ISSUE_K2(s0, 0);
  LOAD_V2(s0);
  __syncthreads();
  WRITE_V2(0, 0);
  asm volatile("s_waitcnt lgkmcnt(0)" ::: "memory");
  __builtin_amdgcn_sched_barrier(0);
  __builtin_amdgcn_s_barrier();
  __builtin_amdgcn_sched_barrier(0);

  const int nt2 = nk >> 7;  // 128-key stages
  int cur = 0;
  for (int t = 0; t < nt2; ++t) {
    const int kt = s0 + t * 128;
    if (t < nt2 - 1) {
      ISSUE_K2(kt + 128, cur ^ 1);
      LOAD_V2(kt + 128);
    }

    COMPUTE_HALF(0, 4 * t);
    COMPUTE_HALF(1, 4 * t + 2);

    if (t < nt2 - 1) {
      asm volatile("s_waitcnt vmcnt(0)" ::: "memory");
      WRITE_V2(cur ^ 1, 4 * (t + 1));
      asm volatile("s_waitcnt lgkmcnt(0)" ::: "memory");
      __builtin_amdgcn_sched_barrier(0);
      __builtin_amdgcn_s_barrier();
      __builtin_amdgcn_sched_barrier(0);
      cur ^= 1;
    }
  }

  if (SPLIT) {
    u16* po = outp + (size_t)split * T_SEQ * 2 * 1024;
#pragma unroll
    for (int mt = 0; mt < 2; ++mt) {
#pragma unroll
      for (int r = 0; r < 4; ++r) {
        int q = q0 + mt * 16 + g * 4 + r;
#pragma unroll
        for (int nt = 0; nt < 4; ++nt)
          po[(rowb + q) * 1024 + h * 64 + nt * 16 + r15] = f2bf(accO[mt][nt][r]);
      }
      if (r15 == 0) {
        int idx = ((split * 2 + b) * 16 + h) * T_SEQ + q0 + mt * 16 + g * 4;
        *(f32x4*)(Ml + idx) = ssum[mt];
      }
    }
  } else {
#pragma unroll
    for (int mt = 0; mt < 2; ++mt)
#pragma unroll
      for (int r = 0; r < 4; ++r) {
        float inv = 1.f / ssum[mt][r];
        int q = q0 + mt * 16 + g * 4 + r;
#pragma unroll
        for (int nt = 0; nt < 4; ++nt)
          outp[(rowb + q) * 1024 + h * 64 + nt * 16 + r15] =
              f2bf(accO[mt][nt][r] * inv);
      }
  }
#undef ISSUE_K2
#undef LOAD_V2
#undef WRITE_V2
#undef COMPUTE_HALF
}

// ---------------- combine two KV-splits (m=0: just l0+l1) ----------------
__global__ __launch_bounds__(256) void attn_combine(
    const u16* __restrict__ part, const float* __restrict__ Ml,
    u16* __restrict__ att) {
  int idx = blockIdx.x * 256 + threadIdx.x;  // (B*T)*(H/8) = 524288
  int row = idx >> 7;                        // b*2048 + q
  int c8 = idx & 127;
  int col = c8 * 8;
  int h = c8 >> 3;
  int b = row >> 11, q = row & 2047;
  float l0 = Ml[(b * 16 + h) * T_SEQ + q];
  float l1 = Ml[((2 + b) * 16 + h) * T_SEQ + q];
  float inv = 1.f / (l0 + l1);
  bf16x8 o0 = *(const bf16x8*)(part + (size_t)row * 1024 + col);
  bf16x8 o1 = *(const bf16x8*)(part + (size_t)T_SEQ * 2 * 1024 +
                               (size_t)row * 1024 + col);
  bf16x8 o;
#pragma unroll
  for (int j = 0; j < 8; ++j)
    o[j] = (short)f2bf((bf2f((u16)o0[j]) + bf2f((u16)o1[j])) * inv);
  *(bf16x8*)(att + (size_t)row * 1024 + col) = o;
}

// ---------------- launch ----------------
extern "C" void kernel_launch(void* const* d_in, const int* in_sizes, int n_in,
                              void* d_out, int out_size, void* d_ws, size_t ws_size,
                              hipStream_t stream) {
  const float* x = (const float*)d_in[0];     // [2,2048,1024] f32
  const int* mask = (const int*)d_in[1];      // [2,1,1,2048] int32
  const float* Wqkv = (const float*)d_in[2];  // [1024,3072] f32
  const float* bqkv = (const float*)d_in[3];  // [3072] f32
  const float* Wout = (const float*)d_in[4];  // [1024,1024] f32
  const float* bout = (const float*)d_in[5];  // [1024] f32
  float* out = (float*)d_out;                 // [2,2048,1024] f32

  const int B = 2, T = 2048, H = 1024, M = B * T;

  u16* qkv = (u16*)d_ws;                       // M*3H
  u16* att = qkv + (size_t)M * 3 * H;          // M*H
  u16* WtQ = att + (size_t)M * H;              // 3H*H
  u16* WtO = WtQ + (size_t)3 * H * H;          // H*H
  u16* part = WtO + (size_t)H * H;             // 2 * M*H  (split partials)
  float* Ml = (float*)(part + (size_t)2 * M * H);  // 2*65536 floats (l only)

  const size_t need = ((size_t)M * 3 * H + (size_t)M * H + (size_t)3 * H * H +
                       (size_t)H * H + (size_t)2 * M * H) * 2 +
                      (size_t)2 * 131072 * 4;
  const bool split = ws_size >= need;

  transpose_f32_bf16<<<dim3(3 * H / 32, H / 32), 256, 0, stream>>>(Wqkv, WtQ, H, 3 * H);
  transpose_f32_bf16<<<dim3(H / 32, H / 32), 256, 0, stream>>>(Wout, WtO, H, H);
  gemm_a32_bf16<<<(3 * H / 128) * (M / 128), 256, 0, stream>>>(x, WtQ, bqkv, qkv, M, 3 * H, H);
  if (split) {
    attn_fwd<true><<<512, 512, 0, stream>>>(qkv, mask, part, Ml, T / 2);
    attn_combine<<<(M * H / 8 + 255) / 256, 256, 0, stream>>>(part, Ml, att);
  } else {
    attn_fwd<false><<<256, 512, 0, stream>>>(qkv, mask, att, Ml, T);
  }
  gemm_bf16<false><<<(H / 128) * (M / 128), 256, 0, stream>>>(att, WtO, bout, out, M, H, H);
}

// Round 14
// 165.937 us; speedup vs baseline: 1.1123x; 1.0034x over previous
//
#include <hip/hip_runtime.h>
#include <stdint.h>

typedef unsigned short u16;
typedef unsigned int u32;
typedef short bf16x8 __attribute__((ext_vector_type(8)));
typedef float f32x4 __attribute__((ext_vector_type(4)));

#define MFMA16(a, b, c) __builtin_amdgcn_mfma_f32_16x16x32_bf16((a), (b), (c), 0, 0, 0)
#define BAR()                              \
  do {                                     \
    __builtin_amdgcn_sched_barrier(0);     \
    __builtin_amdgcn_s_barrier();          \
    __builtin_amdgcn_sched_barrier(0);     \
  } while (0)

__device__ __forceinline__ u16 f2bf(float f) {
  union { float f; u32 u; } v; v.f = f;
  u32 u = v.u;
  u32 r = (u + 0x7FFFu + ((u >> 16) & 1u)) >> 16;  // RNE
  return (u16)r;
}
__device__ __forceinline__ float bf2f(u16 h) {
  union { u32 u; float f; } v; v.u = ((u32)h) << 16;
  return v.f;
}
// packed f32x2 -> bf16x2 (single HW instruction, RNE)
__device__ __forceinline__ u32 cvtpk_bf16(float lo, float hi) {
  u32 r;
  asm("v_cvt_pk_bf16_f32 %0, %1, %2" : "=v"(r) : "v"(lo), "v"(hi));
  return r;
}

// async global->LDS, 16B per lane. LDS base must be wave-uniform (HW adds lane*16).
__device__ __forceinline__ void gload_lds16(const void* g, void* l) {
  __builtin_amdgcn_global_load_lds(
      (const __attribute__((address_space(1))) unsigned int*)g,
      (__attribute__((address_space(3))) unsigned int*)l,
      16, 0, 0);
}

// ---------------- transpose+convert: src f32 [R][C] -> dst bf16 [C][R] ----------------
__global__ __launch_bounds__(256) void transpose_f32_bf16(
    const float* __restrict__ src, u16* __restrict__ dst, int R, int C) {
  __shared__ u16 t[32][33];
  const int bx = blockIdx.x * 32, by = blockIdx.y * 32;
  const int tx = threadIdx.x & 31, ty = threadIdx.x >> 5;  // 32x8
#pragma unroll
  for (int i = 0; i < 32; i += 8)
    t[ty + i][tx] = f2bf(src[(size_t)(by + ty + i) * C + bx + tx]);
  __syncthreads();
#pragma unroll
  for (int i = 0; i < 32; i += 8)
    dst[(size_t)(bx + ty + i) * R + by + tx] = t[tx][ty + i];
}

// ------- qkv GEMM, fused f32->bf16 A path, PIPELINED (T4 counted-drain) -------
// Bs double-buffered; raw barriers; NO vmcnt(0) in the loop. The compiler's own
// vmcnt wait for the A registers at cvt drains B(t) (older) while B(t+1) (newer
// 4 gloads) stays in flight across the whole iteration. A(t+1) issues after
// barrier B and hides under the 32 MFMAs. Cross-wave safe: each wave drains its
// own B(t) before the barrier that precedes compute(t).
__global__ __launch_bounds__(256) void gemm_a32_bf16(
    const float* __restrict__ A, const u16* __restrict__ Bt,
    const float* __restrict__ bias, u16* __restrict__ Cout,
    int M, int N, int K) {
  __shared__ __align__(16) u16 As[128 * 64];
  __shared__ __align__(16) u16 Bs[2][128 * 64];
  const int tid = threadIdx.x;
  const int lane = tid & 63;
  const int wave = tid >> 6;
  const int nwg = gridDim.x;
  const int id = blockIdx.x;
  const int sw = (id & 7) * (nwg >> 3) + (id >> 3);
  const int nx = N >> 7;
  const int m0 = (sw / nx) * 128;
  const int n0 = (sw % nx) * 128;
  const int wm = (wave >> 1) * 64;
  const int wn = (wave & 1) * 64;

  f32x4 acc[4][4] = {};
  const char* Bbase = (const char*)Bt;
  float4 fa[4], fb[4];

  // staging coordinates (compile-time per i)
  // flat = wave*1024 + lane*16 + i*4096 ; row = flat>>7 ; colb = flat&127

  // prologue: issue B(0), load A(0)
#pragma unroll
  for (int i = 0; i < 4; ++i) {
    int flat = wave * 1024 + lane * 16 + i * 4096;
    int row = flat >> 7;
    int colb = flat & 127;
    gload_lds16(Bbase + ((size_t)(n0 + row) * K) * 2 + colb,
                (char*)&Bs[0][0] + flat);
  }
#pragma unroll
  for (int i = 0; i < 4; ++i) {
    int flat = wave * 1024 + lane * 16 + i * 4096;
    int row = flat >> 7;
    int colb = flat & 127;
    const float* ax = A + (size_t)(m0 + row) * K + (colb >> 1);
    fa[i] = *(const float4*)ax;
    fb[i] = *(const float4*)(ax + 4);
  }

  const int nsteps = K >> 6;
  for (int t = 0; t < nsteps; ++t) {
    const int kt = t << 6;
    BAR();  // barrier A: compute(t-1) done everywhere -> As, Bs[other] writable
    if (t < nsteps - 1) {
#pragma unroll
      for (int i = 0; i < 4; ++i) {
        int flat = wave * 1024 + lane * 16 + i * 4096;
        int row = flat >> 7;
        int colb = flat & 127;
        gload_lds16(Bbase + ((size_t)(n0 + row) * K + kt + 64) * 2 + colb,
                    (char*)&Bs[(t & 1) ^ 1][0] + flat);
      }
    }
    // cvt A(t) -> As (compiler inserts vmcnt wait; B(t+1) stays in flight)
#pragma unroll
    for (int i = 0; i < 4; ++i) {
      int flat = wave * 1024 + lane * 16 + i * 4096;
      union { u32 w[4]; bf16x8 v; } o;
      o.w[0] = cvtpk_bf16(fa[i].x, fa[i].y);
      o.w[1] = cvtpk_bf16(fa[i].z, fa[i].w);
      o.w[2] = cvtpk_bf16(fb[i].x, fb[i].y);
      o.w[3] = cvtpk_bf16(fb[i].z, fb[i].w);
      *(bf16x8*)((char*)As + flat) = o.v;
    }
    asm volatile("s_waitcnt lgkmcnt(0)" ::: "memory");
    BAR();  // barrier B: As(t) visible; B(t) complete (drained via A-wait)
    if (t < nsteps - 1) {
#pragma unroll
      for (int i = 0; i < 4; ++i) {
        int flat = wave * 1024 + lane * 16 + i * 4096;
        int row = flat >> 7;
        int colb = flat & 127;
        const float* ax = A + (size_t)(m0 + row) * K + kt + 64 + (colb >> 1);
        fa[i] = *(const float4*)ax;
        fb[i] = *(const float4*)(ax + 4);
      }
    }
#pragma unroll
    for (int ks = 0; ks < 2; ++ks) {
      const int col = (lane >> 4) * 8 + ks * 32;
      bf16x8 af[4], bfr[4];
#pragma unroll
      for (int mt = 0; mt < 4; ++mt)
        af[mt] = *(const bf16x8*)(As + (wm + mt * 16 + (lane & 15)) * 64 + col);
#pragma unroll
      for (int nt = 0; nt < 4; ++nt)
        bfr[nt] = *(const bf16x8*)(&Bs[t & 1][0] +
                                   (wn + nt * 16 + (lane & 15)) * 64 + col);
#pragma unroll
      for (int mt = 0; mt < 4; ++mt)
#pragma unroll
        for (int nt = 0; nt < 4; ++nt)
          acc[mt][nt] = MFMA16(af[mt], bfr[nt], acc[mt][nt]);
    }
  }

  float bv[4];
#pragma unroll
  for (int nt = 0; nt < 4; ++nt)
    bv[nt] = bias[n0 + wn + nt * 16 + (lane & 15)];
#pragma unroll
  for (int mt = 0; mt < 4; ++mt)
#pragma unroll
    for (int nt = 0; nt < 4; ++nt)
#pragma unroll
      for (int r = 0; r < 4; ++r) {
        int m = m0 + wm + mt * 16 + (lane >> 4) * 4 + r;
        int n = n0 + wn + nt * 16 + (lane & 15);
        Cout[(size_t)m * N + n] = f2bf(acc[mt][nt][r] + bv[nt]);
      }
}

// ---------------- GEMM (bf16 A), PIPELINED: As+Bs double-buffered ----------------
// Loop: vmcnt(0)+barrier -> issue AB(t+1) into other buffer -> compute(t).
// AB(t+1)'s latency hides under compute(t); drain happens at top of t+1.
template <bool OUT_BF16>
__global__ __launch_bounds__(256) void gemm_bf16(
    const u16* __restrict__ A, const u16* __restrict__ Bt,
    const float* __restrict__ bias, void* __restrict__ Cout,
    int M, int N, int K) {
  __shared__ __align__(16) u16 As[2][128 * 64];
  __shared__ __align__(16) u16 Bs[2][128 * 64];
  const int tid = threadIdx.x;
  const int lane = tid & 63;
  const int wave = tid >> 6;
  const int nwg = gridDim.x;
  const int id = blockIdx.x;
  const int sw = (id & 7) * (nwg >> 3) + (id >> 3);
  const int nx = N >> 7;
  const int m0 = (sw / nx) * 128;
  const int n0 = (sw % nx) * 128;
  const int wm = (wave >> 1) * 64;
  const int wn = (wave & 1) * 64;

  f32x4 acc[4][4] = {};

  const char* Abase = (const char*)A;
  const char* Bbase = (const char*)Bt;

#define STAGE_AB(ktile, buf)                                                   \
  _Pragma("unroll") for (int i = 0; i < 4; ++i) {                              \
    int flat = wave * 1024 + lane * 16 + i * 4096;                             \
    int row = flat >> 7;                                                       \
    int colb = flat & 127;                                                     \
    gload_lds16(Abase + ((size_t)(m0 + row) * K + (ktile)) * 2 + colb,         \
                (char*)&As[buf][0] + flat);                                    \
    gload_lds16(Bbase + ((size_t)(n0 + row) * K + (ktile)) * 2 + colb,         \
                (char*)&Bs[buf][0] + flat);                                    \
  }

  STAGE_AB(0, 0);

  const int nsteps = K >> 6;
  for (int t = 0; t < nsteps; ++t) {
    asm volatile("s_waitcnt vmcnt(0)" ::: "memory");  // AB(t) landed (mine)
    BAR();                                            // visible to all
    if (t < nsteps - 1) STAGE_AB((t << 6) + 64, (t & 1) ^ 1);
#pragma unroll
    for (int ks = 0; ks < 2; ++ks) {
      const int col = (lane >> 4) * 8 + ks * 32;
      bf16x8 af[4], bfr[4];
#pragma unroll
      for (int mt = 0; mt < 4; ++mt)
        af[mt] = *(const bf16x8*)(&As[t & 1][0] +
                                  (wm + mt * 16 + (lane & 15)) * 64 + col);
#pragma unroll
      for (int nt = 0; nt < 4; ++nt)
        bfr[nt] = *(const bf16x8*)(&Bs[t & 1][0] +
                                   (wn + nt * 16 + (lane & 15)) * 64 + col);
#pragma unroll
      for (int mt = 0; mt < 4; ++mt)
#pragma unroll
        for (int nt = 0; nt < 4; ++nt)
          acc[mt][nt] = MFMA16(af[mt], bfr[nt], acc[mt][nt]);
    }
  }
#undef STAGE_AB

  float bv[4];
#pragma unroll
  for (int nt = 0; nt < 4; ++nt)
    bv[nt] = bias[n0 + wn + nt * 16 + (lane & 15)];
#pragma unroll
  for (int mt = 0; mt < 4; ++mt)
#pragma unroll
    for (int nt = 0; nt < 4; ++nt)
#pragma unroll
      for (int r = 0; r < 4; ++r) {
        int m = m0 + wm + mt * 16 + (lane >> 4) * 4 + r;
        int n = n0 + wn + nt * 16 + (lane & 15);
        float v = acc[mt][nt][r] + bv[nt];
        if (OUT_BF16)
          ((u16*)Cout)[(size_t)m * N + n] = f2bf(v);
        else
          ((float*)Cout)[(size_t)m * N + n] = v;
      }
}

// ---------------- flash attention (v12: permuted-K staging, zero-shuffle PV) ----
// UNCHANGED from round 13 (72.6 us; FETCH 16.5 MB with XCD-affinity grid).
#define T_SEQ 2048
#define ROWQKV 3072
#define SCL 0.180336880f  /* (1/sqrt(64)) * log2(e) */

template <bool SPLIT>
__global__ __launch_bounds__(512) void attn_fwd(
    const u16* __restrict__ qkv, const int* __restrict__ mask,
    u16* __restrict__ outp, float* __restrict__ Ml, int nk) {
  __shared__ __align__(16) u16 Ks[2][2][64 * 64];  // [buf][half][storerow][dk], swz s=row&7
  __shared__ __align__(16) u16 Vt[2][2][64 * 64];  // [buf][half][d][key], swz row^(row>>3)
  __shared__ u32 mkb[64];                          // key-mask bitset (nk bits used)
  __shared__ __align__(16) u32 lut[256 * 4];       // byte -> 8 x bf16 {0,1}

  const int tid = threadIdx.x;
  const int lane = tid & 63;
  const int wave = tid >> 6;
  const int r15 = lane & 15;
  const int g = lane >> 4;
  const int id = blockIdx.x;
  const int hz = ((id >> 6) << 3) | (id & 7);
  const int qb = (id >> 3) & 7;
  const int h = SPLIT ? (hz >> 2) : (hz >> 1);
  const int z = SPLIT ? (hz & 3) : (hz & 1);
  const int split = SPLIT ? (z >> 1) : 0;
  const int b = SPLIT ? (z & 1) : z;
  const int s0 = split * nk;
  const int q0 = qb * 256 + wave * 32;
  const size_t rowb = (size_t)b * T_SEQ;

  for (int i = wave; i < (nk >> 6); i += 8) {
    unsigned long long bm =
        __ballot(mask[b * T_SEQ + s0 + i * 64 + lane] != 0);
    if (lane == 0) {
      mkb[2 * i] = (u32)bm;
      mkb[2 * i + 1] = (u32)(bm >> 32);
    }
  }
  for (int i = tid; i < 256; i += 512) {
    union { u32 w[4]; bf16x8 v; } e;
#pragma unroll
    for (int j = 0; j < 4; ++j)
      e.w[j] = (((i >> (2 * j)) & 1) ? 0x3F80u : 0u) |
               (((i >> (2 * j + 1)) & 1) ? 0x3F800000u : 0u);
    *(bf16x8*)((char*)lut + i * 16) = e.v;
  }

  bf16x8 aq[2][2];
#pragma unroll
  for (int mt = 0; mt < 2; ++mt)
#pragma unroll
    for (int ks = 0; ks < 2; ++ks) {
      bf16x8 t = *(const bf16x8*)(qkv +
          (rowb + q0 + mt * 16 + r15) * ROWQKV + h * 64 + g * 8 + ks * 32);
#pragma unroll
      for (int j = 0; j < 8; ++j) t[j] = (short)f2bf(bf2f((u16)t[j]) * SCL);
      aq[mt][ks] = t;
    }

  f32x4 accO[2][4] = {};
  f32x4 ssum[2] = {};
  bf16x8 vr0, vr1;

#define ISSUE_K2(ktile, buf)                                                   \
  {                                                                            \
    int L = wave * 1024 + lane * 16;                                           \
    int row = L >> 7;                                                          \
    int cb = L & 127;                                                          \
    int scb = cb ^ ((row & 7) << 4);                                           \
    int prow = ((row >> 4) & 1) * 32 + ((row >> 2) & 3) * 8 +                  \
               (row >> 5) * 4 + (row & 3);                                     \
    gload_lds16((const char*)qkv +                                             \
                    ((rowb + (ktile) + prow) * ROWQKV + 1024 + h * 64) * 2 + scb, \
                (char*)&Ks[buf][0][0] + wave * 1024);                          \
    gload_lds16((const char*)qkv +                                             \
                    ((rowb + (ktile) + 64 + prow) * ROWQKV + 1024 + h * 64) * 2 + scb, \
                (char*)&Ks[buf][1][0] + wave * 1024);                          \
  }

#define LOAD_V2(ktile)                                                         \
  {                                                                            \
    vr0 = *(const bf16x8*)(qkv + (rowb + (ktile) + (tid >> 3)) * ROWQKV +      \
                           2048 + h * 64 + (tid & 7) * 8);                     \
    vr1 = *(const bf16x8*)(qkv + (rowb + (ktile) + 64 + (tid >> 3)) * ROWQKV + \
                           2048 + h * 64 + (tid & 7) * 8);                     \
  }

#define WRITE_V2(buf, t4)                                                      \
  {                                                                            \
    int key = tid >> 3;                                                        \
    u32 w0 = mkb[(t4) + (key >> 5)];                                           \
    if (!((w0 >> (key & 31)) & 1u)) {                                          \
      bf16x8 zz = {};                                                          \
      vr0 = zz;                                                                \
    }                                                                          \
    u32 w1 = mkb[(t4) + 2 + (key >> 5)];                                       \
    if (!((w1 >> (key & 31)) & 1u)) {                                          \
      bf16x8 zz = {};                                                          \
      vr1 = zz;                                                                \
    }                                                                          \
    _Pragma("unroll") for (int j = 0; j < 8; ++j) {                            \
      int row = (tid & 7) * 8 + j;                                             \
      int sv = ((row ^ (row >> 3)) & 7) << 4;                                  \
      *(u16*)((char*)&Vt[buf][0][0] + row * 128 + ((key * 2) ^ sv)) =          \
          (u16)vr0[j];                                                         \
      *(u16*)((char*)&Vt[buf][1][0] + row * 128 + ((key * 2) ^ sv)) =          \
          (u16)vr1[j];                                                         \
    }                                                                          \
  }

#define COMPUTE_HALF(H, bw)                                                    \
  {                                                                            \
    f32x4 s[2][4] = {};                                                        \
    _Pragma("unroll") for (int ks = 0; ks < 2; ++ks) {                         \
      bf16x8 bk[4];                                                            \
      _Pragma("unroll") for (int nt = 0; nt < 4; ++nt) {                       \
        int row = nt * 16 + r15;                                               \
        int cb = (g * 8 + ks * 32) * 2;                                        \
        bk[nt] = *(const bf16x8*)((const char*)&Ks[cur][H][0] + row * 128 +    \
                                  (cb ^ ((row & 7) << 4)));                    \
      }                                                                        \
      _Pragma("unroll") for (int mt = 0; mt < 2; ++mt)                         \
        _Pragma("unroll") for (int nt = 0; nt < 4; ++nt)                       \
          s[mt][nt] = MFMA16(bk[nt], aq[mt][ks], s[mt][nt]);                   \
    }                                                                          \
    u32 pk[2][4][2];                                                           \
    _Pragma("unroll") for (int mt = 0; mt < 2; ++mt)                           \
      _Pragma("unroll") for (int nt = 0; nt < 4; ++nt) {                       \
        float e0 = exp2f(s[mt][nt][0]);                                        \
        float e1 = exp2f(s[mt][nt][1]);                                        \
        float e2 = exp2f(s[mt][nt][2]);                                        \
        float e3 = exp2f(s[mt][nt][3]);                                        \
        pk[mt][nt][0] = cvtpk_bf16(e0, e1);                                    \
        pk[mt][nt][1] = cvtpk_bf16(e2, e3);                                    \
      }                                                                        \
    __builtin_amdgcn_s_setprio(1);                                             \
    _Pragma("unroll") for (int ks = 0; ks < 2; ++ks) {                         \
      const int col = g * 8 + ks * 32;                                         \
      bf16x8 bv[4];                                                            \
      _Pragma("unroll") for (int nt = 0; nt < 4; ++nt) {                       \
        int row = nt * 16 + r15;                                               \
        int sv = ((row ^ (row >> 3)) & 7) << 4;                                \
        bv[nt] = *(const bf16x8*)((const char*)&Vt[cur][H][0] + row * 128 +    \
                                  ((col * 2) ^ sv));                           \
      }                                                                        \
      u32 wb = mkb[(bw) + ks];                                                 \
      u32 lb = (wb >> (g * 8)) & 0xFFu;                                        \
      bf16x8 mf = *(const bf16x8*)((const char*)lut + lb * 16);                \
      _Pragma("unroll") for (int mt = 0; mt < 2; ++mt) {                       \
        union { u32 w[4]; bf16x8 v; } ap;                                      \
        ap.w[0] = pk[mt][ks][0];                                               \
        ap.w[1] = pk[mt][ks][1];                                               \
        ap.w[2] = pk[mt][2 + ks][0];                                           \
        ap.w[3] = pk[mt][2 + ks][1];                                           \
        _Pragma("unroll") for (int nt = 0; nt < 4; ++nt)                       \
          accO[mt][nt] = MFMA16(ap.v, bv[nt], accO[mt][nt]);                   \
        ssum[mt] = MFMA16(ap.v, mf, ssum[mt]);                                 \
      }                                                                        \
    }                                                                          \
    __builtin_amdgcn_s_setprio(0);                                             \
  }

  // prologue
  ISSUE_K2(s0, 0);
  LOAD_V2(s0);
  __syncthreads();
  WRITE_V2(0, 0);
  asm volatile("s_waitcnt lgkmcnt(0)" ::: "memory");
  BAR();

  const int nt2 = nk >> 7;  // 128-key stages
  int cur = 0;
  for (int t = 0; t < nt2; ++t) {
    const int kt = s0 + t * 128;
    if (t < nt2 - 1) {
      ISSUE_K2(kt + 128, cur ^ 1);
      LOAD_V2(kt + 128);
    }

    COMPUTE_HALF(0, 4 * t);
    COMPUTE_HALF(1, 4 * t + 2);

    if (t < nt2 - 1) {
      asm volatile("s_waitcnt vmcnt(0)" ::: "memory");
      WRITE_V2(cur ^ 1, 4 * (t + 1));
      asm volatile("s_waitcnt lgkmcnt(0)" ::: "memory");
      BAR();
      cur ^= 1;
    }
  }

  if (SPLIT) {
    u16* po = outp + (size_t)split * T_SEQ * 2 * 1024;
#pragma unroll
    for (int mt = 0; mt < 2; ++mt) {
#pragma unroll
      for (int r = 0; r < 4; ++r) {
        int q = q0 + mt * 16 + g * 4 + r;
#pragma unroll
        for (int nt = 0; nt < 4; ++nt)
          po[(rowb + q) * 1024 + h * 64 + nt * 16 + r15] = f2bf(accO[mt][nt][r]);
      }
      if (r15 == 0) {
        int idx = ((split * 2 + b) * 16 + h) * T_SEQ + q0 + mt * 16 + g * 4;
        *(f32x4*)(Ml + idx) = ssum[mt];
      }
    }
  } else {
#pragma unroll
    for (int mt = 0; mt < 2; ++mt)
#pragma unroll
      for (int r = 0; r < 4; ++r) {
        float inv = 1.f / ssum[mt][r];
        int q = q0 + mt * 16 + g * 4 + r;
#pragma unroll
        for (int nt = 0; nt < 4; ++nt)
          outp[(rowb + q) * 1024 + h * 64 + nt * 16 + r15] =
              f2bf(accO[mt][nt][r] * inv);
      }
  }
#undef ISSUE_K2
#undef LOAD_V2
#undef WRITE_V2
#undef COMPUTE_HALF
}

// ---------------- combine two KV-splits (m=0: just l0+l1) ----------------
__global__ __launch_bounds__(256) void attn_combine(
    const u16* __restrict__ part, const float* __restrict__ Ml,
    u16* __restrict__ att) {
  int idx = blockIdx.x * 256 + threadIdx.x;  // (B*T)*(H/8) = 524288
  int row = idx >> 7;                        // b*2048 + q
  int c8 = idx & 127;
  int col = c8 * 8;
  int h = c8 >> 3;
  int b = row >> 11, q = row & 2047;
  float l0 = Ml[(b * 16 + h) * T_SEQ + q];
  float l1 = Ml[((2 + b) * 16 + h) * T_SEQ + q];
  float inv = 1.f / (l0 + l1);
  bf16x8 o0 = *(const bf16x8*)(part + (size_t)row * 1024 + col);
  bf16x8 o1 = *(const bf16x8*)(part + (size_t)T_SEQ * 2 * 1024 +
                               (size_t)row * 1024 + col);
  bf16x8 o;
#pragma unroll
  for (int j = 0; j < 8; ++j)
    o[j] = (short)f2bf((bf2f((u16)o0[j]) + bf2f((u16)o1[j])) * inv);
  *(bf16x8*)(att + (size_t)row * 1024 + col) = o;
}

// ---------------- launch ----------------
extern "C" void kernel_launch(void* const* d_in, const int* in_sizes, int n_in,
                              void* d_out, int out_size, void* d_ws, size_t ws_size,
                              hipStream_t stream) {
  const float* x = (const float*)d_in[0];     // [2,2048,1024] f32
  const int* mask = (const int*)d_in[1];      // [2,1,1,2048] int32
  const float* Wqkv = (const float*)d_in[2];  // [1024,3072] f32
  const float* bqkv = (const float*)d_in[3];  // [3072] f32
  const float* Wout = (const float*)d_in[4];  // [1024,1024] f32
  const float* bout = (const float*)d_in[5];  // [1024] f32
  float* out = (float*)d_out;                 // [2,2048,1024] f32

  const int B = 2, T = 2048, H = 1024, M = B * T;

  u16* qkv = (u16*)d_ws;                       // M*3H
  u16* att = qkv + (size_t)M * 3 * H;          // M*H
  u16* WtQ = att + (size_t)M * H;              // 3H*H
  u16* WtO = WtQ + (size_t)3 * H * H;          // H*H
  u16* part = WtO + (size_t)H * H;             // 2 * M*H  (split partials)
  float* Ml = (float*)(part + (size_t)2 * M * H);  // 2*65536 floats (l only)

  const size_t need = ((size_t)M * 3 * H + (size_t)M * H + (size_t)3 * H * H +
                       (size_t)H * H + (size_t)2 * M * H) * 2 +
                      (size_t)2 * 131072 * 4;
  const bool split = ws_size >= need;

  transpose_f32_bf16<<<dim3(3 * H / 32, H / 32), 256, 0, stream>>>(Wqkv, WtQ, H, 3 * H);
  transpose_f32_bf16<<<dim3(H / 32, H / 32), 256, 0, stream>>>(Wout, WtO, H, H);
  gemm_a32_bf16<<<(3 * H / 128) * (M / 128), 256, 0, stream>>>(x, WtQ, bqkv, qkv, M, 3 * H, H);
  if (split) {
    attn_fwd<true><<<512, 512, 0, stream>>>(qkv, mask, part, Ml, T / 2);
    attn_combine<<<(M * H / 8 + 255) / 256, 256, 0, stream>>>(part, Ml, att);
  } else {
    attn_fwd<false><<<256, 512, 0, stream>>>(qkv, mask, att, Ml, T);
  }
  gemm_bf16<false><<<(H / 128) * (M / 128), 256, 0, stream>>>(att, WtO, bout, out, M, H, H);
}

// Round 15
// 152.550 us; speedup vs baseline: 1.2099x; 1.0878x over previous
//
#include <hip/hip_runtime.h>
#include <stdint.h>

typedef unsigned short u16;
typedef unsigned int u32;
typedef short bf16x8 __attribute__((ext_vector_type(8)));
typedef float f32x4 __attribute__((ext_vector_type(4)));

#define MFMA16(a, b, c) __builtin_amdgcn_mfma_f32_16x16x32_bf16((a), (b), (c), 0, 0, 0)
#define BAR()                              \
  do {                                     \
    __builtin_amdgcn_sched_barrier(0);     \
    __builtin_amdgcn_s_barrier();          \
    __builtin_amdgcn_sched_barrier(0);     \
  } while (0)

__device__ __forceinline__ u16 f2bf(float f) {
  union { float f; u32 u; } v; v.f = f;
  u32 u = v.u;
  u32 r = (u + 0x7FFFu + ((u >> 16) & 1u)) >> 16;  // RNE
  return (u16)r;
}
__device__ __forceinline__ float bf2f(u16 h) {
  union { u32 u; float f; } v; v.u = ((u32)h) << 16;
  return v.f;
}
// packed f32x2 -> bf16x2 (single HW instruction, RNE)
__device__ __forceinline__ u32 cvtpk_bf16(float lo, float hi) {
  u32 r;
  asm("v_cvt_pk_bf16_f32 %0, %1, %2" : "=v"(r) : "v"(lo), "v"(hi));
  return r;
}

// async global->LDS, 16B per lane. LDS base must be wave-uniform (HW adds lane*16).
__device__ __forceinline__ void gload_lds16(const void* g, void* l) {
  __builtin_amdgcn_global_load_lds(
      (const __attribute__((address_space(1))) unsigned int*)g,
      (__attribute__((address_space(3))) unsigned int*)l,
      16, 0, 0);
}

// ---------------- transpose+convert: src f32 [R][C] -> dst bf16 [C][R] ----------------
__global__ __launch_bounds__(256) void transpose_f32_bf16(
    const float* __restrict__ src, u16* __restrict__ dst, int R, int C) {
  __shared__ u16 t[32][33];
  const int bx = blockIdx.x * 32, by = blockIdx.y * 32;
  const int tx = threadIdx.x & 31, ty = threadIdx.x >> 5;  // 32x8
#pragma unroll
  for (int i = 0; i < 32; i += 8)
    t[ty + i][tx] = f2bf(src[(size_t)(by + ty + i) * C + bx + tx]);
  __syncthreads();
#pragma unroll
  for (int i = 0; i < 32; i += 8)
    dst[(size_t)(bx + ty + i) * R + by + tx] = t[tx][ty + i];
}

// ------- qkv GEMM, fused f32->bf16 A, single-barrier pipeline + T2 swizzle -------
// Per step: issue B(t+1) (gload_lds, pre-swizzled src) -> issue A(t+1) f32 loads
// -> MFMA(t) (covers A/B latency) -> cvt A(t+1)->As[other] (implicit vmcnt wait;
// in-order vmcnt means B(t+1), issued earlier, is also complete) -> lgkm(0) ->
// ONE barrier. All LDS tiles XOR-swizzled (byte ^= (row&7)<<4) on both sides.
__global__ __launch_bounds__(256) void gemm_a32_bf16(
    const float* __restrict__ A, const u16* __restrict__ Bt,
    const float* __restrict__ bias, u16* __restrict__ Cout,
    int M, int N, int K) {
  __shared__ __align__(16) u16 As[2][128 * 64];
  __shared__ __align__(16) u16 Bs[2][128 * 64];
  const int tid = threadIdx.x;
  const int lane = tid & 63;
  const int wave = tid >> 6;
  const int nwg = gridDim.x;
  const int id = blockIdx.x;
  const int sw = (id & 7) * (nwg >> 3) + (id >> 3);
  const int nx = N >> 7;
  const int m0 = (sw / nx) * 128;
  const int n0 = (sw % nx) * 128;
  const int wm = (wave >> 1) * 64;
  const int wn = (wave & 1) * 64;

  f32x4 acc[4][4] = {};
  const char* Bbase = (const char*)Bt;
  float4 fa[4], fb[4];

#define A32_ISSUE_B(ktile, buf)                                                \
  _Pragma("unroll") for (int i = 0; i < 4; ++i) {                              \
    int flat = wave * 1024 + lane * 16 + i * 4096;                             \
    int row = flat >> 7;                                                       \
    int cb = flat & 127;                                                       \
    int scb = cb ^ ((row & 7) << 4);                                           \
    gload_lds16(Bbase + ((size_t)(n0 + row) * K + (ktile)) * 2 + scb,          \
                (char*)&Bs[buf][0] + flat);                                    \
  }

#define A32_LOAD_A(ktile)                                                      \
  _Pragma("unroll") for (int i = 0; i < 4; ++i) {                              \
    int flat = wave * 1024 + lane * 16 + i * 4096;                             \
    int row = flat >> 7;                                                       \
    int cb = flat & 127;                                                       \
    const float* ax = A + (size_t)(m0 + row) * K + (ktile) + (cb >> 1);        \
    fa[i] = *(const float4*)ax;                                                \
    fb[i] = *(const float4*)(ax + 4);                                          \
  }

#define A32_CVT(buf)                                                           \
  _Pragma("unroll") for (int i = 0; i < 4; ++i) {                              \
    int flat = wave * 1024 + lane * 16 + i * 4096;                             \
    int row = flat >> 7;                                                       \
    int cb = flat & 127;                                                       \
    union { u32 w[4]; bf16x8 v; } o;                                           \
    o.w[0] = cvtpk_bf16(fa[i].x, fa[i].y);                                     \
    o.w[1] = cvtpk_bf16(fa[i].z, fa[i].w);                                     \
    o.w[2] = cvtpk_bf16(fb[i].x, fb[i].y);                                     \
    o.w[3] = cvtpk_bf16(fb[i].z, fb[i].w);                                     \
    *(bf16x8*)((char*)&As[buf][0] + row * 128 + (cb ^ ((row & 7) << 4))) = o.v; \
  }

  // prologue: stage tile 0 (one exposed wait, once)
  A32_ISSUE_B(0, 0);
  A32_LOAD_A(0);
  A32_CVT(0);
  asm volatile("s_waitcnt lgkmcnt(0)" ::: "memory");
  BAR();

  const int nsteps = K >> 6;
  for (int t = 0; t < nsteps; ++t) {
    if (t < nsteps - 1) {
      A32_ISSUE_B((t << 6) + 64, (t & 1) ^ 1);
      A32_LOAD_A((t << 6) + 64);
    }
    __builtin_amdgcn_sched_barrier(0);  // keep issues above the MFMA block
#pragma unroll
    for (int ks = 0; ks < 2; ++ks) {
      const int col = (lane >> 4) * 8 + ks * 32;
      bf16x8 af[4], bfr[4];
#pragma unroll
      for (int mt = 0; mt < 4; ++mt) {
        int row = wm + mt * 16 + (lane & 15);
        af[mt] = *(const bf16x8*)((const char*)&As[t & 1][0] + row * 128 +
                                  ((col * 2) ^ ((row & 7) << 4)));
      }
#pragma unroll
      for (int nt = 0; nt < 4; ++nt) {
        int row = wn + nt * 16 + (lane & 15);
        bfr[nt] = *(const bf16x8*)((const char*)&Bs[t & 1][0] + row * 128 +
                                   ((col * 2) ^ ((row & 7) << 4)));
      }
#pragma unroll
      for (int mt = 0; mt < 4; ++mt)
#pragma unroll
        for (int nt = 0; nt < 4; ++nt)
          acc[mt][nt] = MFMA16(af[mt], bfr[nt], acc[mt][nt]);
    }
    __builtin_amdgcn_sched_barrier(0);  // keep cvt below the MFMA block
    if (t < nsteps - 1) {
      A32_CVT((t & 1) ^ 1);  // vmcnt wait here: A(t+1) done => B(t+1) done
      asm volatile("s_waitcnt lgkmcnt(0)" ::: "memory");
      BAR();
    }
  }
#undef A32_ISSUE_B
#undef A32_LOAD_A
#undef A32_CVT

  float bv[4];
#pragma unroll
  for (int nt = 0; nt < 4; ++nt)
    bv[nt] = bias[n0 + wn + nt * 16 + (lane & 15)];
#pragma unroll
  for (int mt = 0; mt < 4; ++mt)
#pragma unroll
    for (int nt = 0; nt < 4; ++nt)
#pragma unroll
      for (int r = 0; r < 4; ++r) {
        int m = m0 + wm + mt * 16 + (lane >> 4) * 4 + r;
        int n = n0 + wn + nt * 16 + (lane & 15);
        Cout[(size_t)m * N + n] = f2bf(acc[mt][nt][r] + bv[nt]);
      }
}

// ---------------- GEMM (bf16 A), pipelined dbuf + T2 swizzle ----------------
template <bool OUT_BF16>
__global__ __launch_bounds__(256) void gemm_bf16(
    const u16* __restrict__ A, const u16* __restrict__ Bt,
    const float* __restrict__ bias, void* __restrict__ Cout,
    int M, int N, int K) {
  __shared__ __align__(16) u16 As[2][128 * 64];
  __shared__ __align__(16) u16 Bs[2][128 * 64];
  const int tid = threadIdx.x;
  const int lane = tid & 63;
  const int wave = tid >> 6;
  const int nwg = gridDim.x;
  const int id = blockIdx.x;
  const int sw = (id & 7) * (nwg >> 3) + (id >> 3);
  const int nx = N >> 7;
  const int m0 = (sw / nx) * 128;
  const int n0 = (sw % nx) * 128;
  const int wm = (wave >> 1) * 64;
  const int wn = (wave & 1) * 64;

  f32x4 acc[4][4] = {};

  const char* Abase = (const char*)A;
  const char* Bbase = (const char*)Bt;

#define STAGE_AB(ktile, buf)                                                   \
  _Pragma("unroll") for (int i = 0; i < 4; ++i) {                              \
    int flat = wave * 1024 + lane * 16 + i * 4096;                             \
    int row = flat >> 7;                                                       \
    int cb = flat & 127;                                                       \
    int scb = cb ^ ((row & 7) << 4);                                           \
    gload_lds16(Abase + ((size_t)(m0 + row) * K + (ktile)) * 2 + scb,          \
                (char*)&As[buf][0] + flat);                                    \
    gload_lds16(Bbase + ((size_t)(n0 + row) * K + (ktile)) * 2 + scb,         \
                (char*)&Bs[buf][0] + flat);                                    \
  }

  STAGE_AB(0, 0);

  const int nsteps = K >> 6;
  for (int t = 0; t < nsteps; ++t) {
    asm volatile("s_waitcnt vmcnt(0)" ::: "memory");  // AB(t) landed (mine)
    BAR();                                            // visible to all
    if (t < nsteps - 1) STAGE_AB((t << 6) + 64, (t & 1) ^ 1);
#pragma unroll
    for (int ks = 0; ks < 2; ++ks) {
      const int col = (lane >> 4) * 8 + ks * 32;
      bf16x8 af[4], bfr[4];
#pragma unroll
      for (int mt = 0; mt < 4; ++mt) {
        int row = wm + mt * 16 + (lane & 15);
        af[mt] = *(const bf16x8*)((const char*)&As[t & 1][0] + row * 128 +
                                  ((col * 2) ^ ((row & 7) << 4)));
      }
#pragma unroll
      for (int nt = 0; nt < 4; ++nt) {
        int row = wn + nt * 16 + (lane & 15);
        bfr[nt] = *(const bf16x8*)((const char*)&Bs[t & 1][0] + row * 128 +
                                   ((col * 2) ^ ((row & 7) << 4)));
      }
#pragma unroll
      for (int mt = 0; mt < 4; ++mt)
#pragma unroll
        for (int nt = 0; nt < 4; ++nt)
          acc[mt][nt] = MFMA16(af[mt], bfr[nt], acc[mt][nt]);
    }
  }
#undef STAGE_AB

  float bv[4];
#pragma unroll
  for (int nt = 0; nt < 4; ++nt)
    bv[nt] = bias[n0 + wn + nt * 16 + (lane & 15)];
#pragma unroll
  for (int mt = 0; mt < 4; ++mt)
#pragma unroll
    for (int nt = 0; nt < 4; ++nt)
#pragma unroll
      for (int r = 0; r < 4; ++r) {
        int m = m0 + wm + mt * 16 + (lane >> 4) * 4 + r;
        int n = n0 + wn + nt * 16 + (lane & 15);
        float v = acc[mt][nt][r] + bv[nt];
        if (OUT_BF16)
          ((u16*)Cout)[(size_t)m * N + n] = f2bf(v);
        else
          ((float*)Cout)[(size_t)m * N + n] = v;
      }
}

// ---------------- flash attention (v12: permuted-K staging, zero-shuffle PV) ----
// UNCHANGED from round 13/14 (72.2 us; FETCH 16.5 MB; conflicts 2.1e6).
#define T_SEQ 2048
#define ROWQKV 3072
#define SCL 0.180336880f  /* (1/sqrt(64)) * log2(e) */

template <bool SPLIT>
__global__ __launch_bounds__(512) void attn_fwd(
    const u16* __restrict__ qkv, const int* __restrict__ mask,
    u16* __restrict__ outp, float* __restrict__ Ml, int nk) {
  __shared__ __align__(16) u16 Ks[2][2][64 * 64];  // [buf][half][storerow][dk], swz s=row&7
  __shared__ __align__(16) u16 Vt[2][2][64 * 64];  // [buf][half][d][key], swz row^(row>>3)
  __shared__ u32 mkb[64];                          // key-mask bitset (nk bits used)
  __shared__ __align__(16) u32 lut[256 * 4];       // byte -> 8 x bf16 {0,1}

  const int tid = threadIdx.x;
  const int lane = tid & 63;
  const int wave = tid >> 6;
  const int r15 = lane & 15;
  const int g = lane >> 4;
  const int id = blockIdx.x;
  const int hz = ((id >> 6) << 3) | (id & 7);
  const int qb = (id >> 3) & 7;
  const int h = SPLIT ? (hz >> 2) : (hz >> 1);
  const int z = SPLIT ? (hz & 3) : (hz & 1);
  const int split = SPLIT ? (z >> 1) : 0;
  const int b = SPLIT ? (z & 1) : z;
  const int s0 = split * nk;
  const int q0 = qb * 256 + wave * 32;
  const size_t rowb = (size_t)b * T_SEQ;

  for (int i = wave; i < (nk >> 6); i += 8) {
    unsigned long long bm =
        __ballot(mask[b * T_SEQ + s0 + i * 64 + lane] != 0);
    if (lane == 0) {
      mkb[2 * i] = (u32)bm;
      mkb[2 * i + 1] = (u32)(bm >> 32);
    }
  }
  for (int i = tid; i < 256; i += 512) {
    union { u32 w[4]; bf16x8 v; } e;
#pragma unroll
    for (int j = 0; j < 4; ++j)
      e.w[j] = (((i >> (2 * j)) & 1) ? 0x3F80u : 0u) |
               (((i >> (2 * j + 1)) & 1) ? 0x3F800000u : 0u);
    *(bf16x8*)((char*)lut + i * 16) = e.v;
  }

  bf16x8 aq[2][2];
#pragma unroll
  for (int mt = 0; mt < 2; ++mt)
#pragma unroll
    for (int ks = 0; ks < 2; ++ks) {
      bf16x8 t = *(const bf16x8*)(qkv +
          (rowb + q0 + mt * 16 + r15) * ROWQKV + h * 64 + g * 8 + ks * 32);
#pragma unroll
      for (int j = 0; j < 8; ++j) t[j] = (short)f2bf(bf2f((u16)t[j]) * SCL);
      aq[mt][ks] = t;
    }

  f32x4 accO[2][4] = {};
  f32x4 ssum[2] = {};
  bf16x8 vr0, vr1;

#define ISSUE_K2(ktile, buf)                                                   \
  {                                                                            \
    int L = wave * 1024 + lane * 16;                                           \
    int row = L >> 7;                                                          \
    int cb = L & 127;                                                          \
    int scb = cb ^ ((row & 7) << 4);                                           \
    int prow = ((row >> 4) & 1) * 32 + ((row >> 2) & 3) * 8 +                  \
               (row >> 5) * 4 + (row & 3);                                     \
    gload_lds16((const char*)qkv +                                             \
                    ((rowb + (ktile) + prow) * ROWQKV + 1024 + h * 64) * 2 + scb, \
                (char*)&Ks[buf][0][0] + wave * 1024);                          \
    gload_lds16((const char*)qkv +                                             \
                    ((rowb + (ktile) + 64 + prow) * ROWQKV + 1024 + h * 64) * 2 + scb, \
                (char*)&Ks[buf][1][0] + wave * 1024);                          \
  }

#define LOAD_V2(ktile)                                                         \
  {                                                                            \
    vr0 = *(const bf16x8*)(qkv + (rowb + (ktile) + (tid >> 3)) * ROWQKV +      \
                           2048 + h * 64 + (tid & 7) * 8);                     \
    vr1 = *(const bf16x8*)(qkv + (rowb + (ktile) + 64 + (tid >> 3)) * ROWQKV + \
                           2048 + h * 64 + (tid & 7) * 8);                     \
  }

#define WRITE_V2(buf, t4)                                                      \
  {                                                                            \
    int key = tid >> 3;                                                        \
    u32 w0 = mkb[(t4) + (key >> 5)];                                           \
    if (!((w0 >> (key & 31)) & 1u)) {                                          \
      bf16x8 zz = {};                                                          \
      vr0 = zz;                                                                \
    }                                                                          \
    u32 w1 = mkb[(t4) + 2 + (key >> 5)];                                       \
    if (!((w1 >> (key & 31)) & 1u)) {                                          \
      bf16x8 zz = {};                                                          \
      vr1 = zz;                                                                \
    }                                                                          \
    _Pragma("unroll") for (int j = 0; j < 8; ++j) {                            \
      int row = (tid & 7) * 8 + j;                                             \
      int sv = ((row ^ (row >> 3)) & 7) << 4;                                  \
      *(u16*)((char*)&Vt[buf][0][0] + row * 128 + ((key * 2) ^ sv)) =          \
          (u16)vr0[j];                                                         \
      *(u16*)((char*)&Vt[buf][1][0] + row * 128 + ((key * 2) ^ sv)) =          \
          (u16)vr1[j];                                                         \
    }                                                                          \
  }

#define COMPUTE_HALF(H, bw)                                                    \
  {                                                                            \
    f32x4 s[2][4] = {};                                                        \
    _Pragma("unroll") for (int ks = 0; ks < 2; ++ks) {                         \
      bf16x8 bk[4];                                                            \
      _Pragma("unroll") for (int nt = 0; nt < 4; ++nt) {                       \
        int row = nt * 16 + r15;                                               \
        int cb = (g * 8 + ks * 32) * 2;                                        \
        bk[nt] = *(const bf16x8*)((const char*)&Ks[cur][H][0] + row * 128 +    \
                                  (cb ^ ((row & 7) << 4)));                    \
      }                                                                        \
      _Pragma("unroll") for (int mt = 0; mt < 2; ++mt)                         \
        _Pragma("unroll") for (int nt = 0; nt < 4; ++nt)                       \
          s[mt][nt] = MFMA16(bk[nt], aq[mt][ks], s[mt][nt]);                   \
    }                                                                          \
    u32 pk[2][4][2];                                                           \
    _Pragma("unroll") for (int mt = 0; mt < 2; ++mt)                           \
      _Pragma("unroll") for (int nt = 0; nt < 4; ++nt) {                       \
        float e0 = exp2f(s[mt][nt][0]);                                        \
        float e1 = exp2f(s[mt][nt][1]);                                        \
        float e2 = exp2f(s[mt][nt][2]);                                        \
        float e3 = exp2f(s[mt][nt][3]);                                        \
        pk[mt][nt][0] = cvtpk_bf16(e0, e1);                                    \
        pk[mt][nt][1] = cvtpk_bf16(e2, e3);                                    \
      }                                                                        \
    __builtin_amdgcn_s_setprio(1);                                             \
    _Pragma("unroll") for (int ks = 0; ks < 2; ++ks) {                         \
      const int col = g * 8 + ks * 32;                                         \
      bf16x8 bv[4];                                                            \
      _Pragma("unroll") for (int nt = 0; nt < 4; ++nt) {                       \
        int row = nt * 16 + r15;                                               \
        int sv = ((row ^ (row >> 3)) & 7) << 4;                                \
        bv[nt] = *(const bf16x8*)((const char*)&Vt[cur][H][0] + row * 128 +    \
                                  ((col * 2) ^ sv));                           \
      }                                                                        \
      u32 wb = mkb[(bw) + ks];                                                 \
      u32 lb = (wb >> (g * 8)) & 0xFFu;                                        \
      bf16x8 mf = *(const bf16x8*)((const char*)lut + lb * 16);                \
      _Pragma("unroll") for (int mt = 0; mt < 2; ++mt) {                       \
        union { u32 w[4]; bf16x8 v; } ap;                                      \
        ap.w[0] = pk[mt][ks][0];                                               \
        ap.w[1] = pk[mt][ks][1];                                               \
        ap.w[2] = pk[mt][2 + ks][0];                                           \
        ap.w[3] = pk[mt][2 + ks][1];                                           \
        _Pragma("unroll") for (int nt = 0; nt < 4; ++nt)                       \
          accO[mt][nt] = MFMA16(ap.v, bv[nt], accO[mt][nt]);                   \
        ssum[mt] = MFMA16(ap.v, mf, ssum[mt]);                                 \
      }                                                                        \
    }                                                                          \
    __builtin_amdgcn_s_setprio(0);                                             \
  }

  // prologue
  ISSUE_K2(s0, 0);
  LOAD_V2(s0);
  __syncthreads();
  WRITE_V2(0, 0);
  asm volatile("s_waitcnt lgkmcnt(0)" ::: "memory");
  BAR();

  const int nt2 = nk >> 7;  // 128-key stages
  int cur = 0;
  for (int t = 0; t < nt2; ++t) {
    const int kt = s0 + t * 128;
    if (t < nt2 - 1) {
      ISSUE_K2(kt + 128, cur ^ 1);
      LOAD_V2(kt + 128);
    }

    COMPUTE_HALF(0, 4 * t);
    COMPUTE_HALF(1, 4 * t + 2);

    if (t < nt2 - 1) {
      asm volatile("s_waitcnt vmcnt(0)" ::: "memory");
      WRITE_V2(cur ^ 1, 4 * (t + 1));
      asm volatile("s_waitcnt lgkmcnt(0)" ::: "memory");
      BAR();
      cur ^= 1;
    }
  }

  if (SPLIT) {
    u16* po = outp + (size_t)split * T_SEQ * 2 * 1024;
#pragma unroll
    for (int mt = 0; mt < 2; ++mt) {
#pragma unroll
      for (int r = 0; r < 4; ++r) {
        int q = q0 + mt * 16 + g * 4 + r;
#pragma unroll
        for (int nt = 0; nt < 4; ++nt)
          po[(rowb + q) * 1024 + h * 64 + nt * 16 + r15] = f2bf(accO[mt][nt][r]);
      }
      if (r15 == 0) {
        int idx = ((split * 2 + b) * 16 + h) * T_SEQ + q0 + mt * 16 + g * 4;
        *(f32x4*)(Ml + idx) = ssum[mt];
      }
    }
  } else {
#pragma unroll
    for (int mt = 0; mt < 2; ++mt)
#pragma unroll
      for (int r = 0; r < 4; ++r) {
        float inv = 1.f / ssum[mt][r];
        int q = q0 + mt * 16 + g * 4 + r;
#pragma unroll
        for (int nt = 0; nt < 4; ++nt)
          outp[(rowb + q) * 1024 + h * 64 + nt * 16 + r15] =
              f2bf(accO[mt][nt][r] * inv);
      }
  }
#undef ISSUE_K2
#undef LOAD_V2
#undef WRITE_V2
#undef COMPUTE_HALF
}

// ---------------- combine two KV-splits (m=0: just l0+l1) ----------------
__global__ __launch_bounds__(256) void attn_combine(
    const u16* __restrict__ part, const float* __restrict__ Ml,
    u16* __restrict__ att) {
  int idx = blockIdx.x * 256 + threadIdx.x;  // (B*T)*(H/8) = 524288
  int row = idx >> 7;                        // b*2048 + q
  int c8 = idx & 127;
  int col = c8 * 8;
  int h = c8 >> 3;
  int b = row >> 11, q = row & 2047;
  float l0 = Ml[(b * 16 + h) * T_SEQ + q];
  float l1 = Ml[((2 + b) * 16 + h) * T_SEQ + q];
  float inv = 1.f / (l0 + l1);
  bf16x8 o0 = *(const bf16x8*)(part + (size_t)row * 1024 + col);
  bf16x8 o1 = *(const bf16x8*)(part + (size_t)T_SEQ * 2 * 1024 +
                               (size_t)row * 1024 + col);
  bf16x8 o;
#pragma unroll
  for (int j = 0; j < 8; ++j)
    o[j] = (short)f2bf((bf2f((u16)o0[j]) + bf2f((u16)o1[j])) * inv);
  *(bf16x8*)(att + (size_t)row * 1024 + col) = o;
}

// ---------------- launch ----------------
extern "C" void kernel_launch(void* const* d_in, const int* in_sizes, int n_in,
                              void* d_out, int out_size, void* d_ws, size_t ws_size,
                              hipStream_t stream) {
  const float* x = (const float*)d_in[0];     // [2,2048,1024] f32
  const int* mask = (const int*)d_in[1];      // [2,1,1,2048] int32
  const float* Wqkv = (const float*)d_in[2];  // [1024,3072] f32
  const float* bqkv = (const float*)d_in[3];  // [3072] f32
  const float* Wout = (const float*)d_in[4];  // [1024,1024] f32
  const float* bout = (const float*)d_in[5];  // [1024] f32
  float* out = (float*)d_out;                 // [2,2048,1024] f32

  const int B = 2, T = 2048, H = 1024, M = B * T;

  u16* qkv = (u16*)d_ws;                       // M*3H
  u16* att = qkv + (size_t)M * 3 * H;          // M*H
  u16* WtQ = att + (size_t)M * H;              // 3H*H
  u16* WtO = WtQ + (size_t)3 * H * H;          // H*H
  u16* part = WtO + (size_t)H * H;             // 2 * M*H  (split partials)
  float* Ml = (float*)(part + (size_t)2 * M * H);  // 2*65536 floats (l only)

  const size_t need = ((size_t)M * 3 * H + (size_t)M * H + (size_t)3 * H * H +
                       (size_t)H * H + (size_t)2 * M * H) * 2 +
                      (size_t)2 * 131072 * 4;
  const bool split = ws_size >= need;

  transpose_f32_bf16<<<dim3(3 * H / 32, H / 32), 256, 0, stream>>>(Wqkv, WtQ, H, 3 * H);
  transpose_f32_bf16<<<dim3(H / 32, H / 32), 256, 0, stream>>>(Wout, WtO, H, H);
  gemm_a32_bf16<<<(3 * H / 128) * (M / 128), 256, 0, stream>>>(x, WtQ, bqkv, qkv, M, 3 * H, H);
  if (split) {
    attn_fwd<true><<<512, 512, 0, stream>>>(qkv, mask, part, Ml, T / 2);
    attn_combine<<<(M * H / 8 + 255) / 256, 256, 0, stream>>>(part, Ml, att);
  } else {
    attn_fwd<false><<<256, 512, 0, stream>>>(qkv, mask, att, Ml, T);
  }
  gemm_bf16<false><<<(H / 128) * (M / 128), 256, 0, stream>>>(att, WtO, bout, out, M, H, H);
}

// Round 16
// 133.529 us; speedup vs baseline: 1.3822x; 1.1424x over previous
//
#include <hip/hip_runtime.h>
#include <stdint.h>

typedef unsigned short u16;
typedef unsigned int u32;
typedef short bf16x8 __attribute__((ext_vector_type(8)));
typedef float f32x4 __attribute__((ext_vector_type(4)));

#define MFMA16(a, b, c) __builtin_amdgcn_mfma_f32_16x16x32_bf16((a), (b), (c), 0, 0, 0)
#define BAR()                              \
  do {                                     \
    __builtin_amdgcn_sched_barrier(0);     \
    __builtin_amdgcn_s_barrier();          \
    __builtin_amdgcn_sched_barrier(0);     \
  } while (0)

__device__ __forceinline__ u16 f2bf(float f) {
  union { float f; u32 u; } v; v.f = f;
  u32 u = v.u;
  u32 r = (u + 0x7FFFu + ((u >> 16) & 1u)) >> 16;  // RNE
  return (u16)r;
}
__device__ __forceinline__ float bf2f(u16 h) {
  union { u32 u; float f; } v; v.u = ((u32)h) << 16;
  return v.f;
}
// packed f32x2 -> bf16x2 (single HW instruction, RNE)
__device__ __forceinline__ u32 cvtpk_bf16(float lo, float hi) {
  u32 r;
  asm("v_cvt_pk_bf16_f32 %0, %1, %2" : "=v"(r) : "v"(lo), "v"(hi));
  return r;
}

// async global->LDS, 16B per lane. LDS base must be wave-uniform (HW adds lane*16).
__device__ __forceinline__ void gload_lds16(const void* g, void* l) {
  __builtin_amdgcn_global_load_lds(
      (const __attribute__((address_space(1))) unsigned int*)g,
      (__attribute__((address_space(3))) unsigned int*)l,
      16, 0, 0);
}

// ---------------- transpose+convert: src f32 [R][C] -> dst bf16 [C][R] ----------------
__global__ __launch_bounds__(256) void transpose_f32_bf16(
    const float* __restrict__ src, u16* __restrict__ dst, int R, int C) {
  __shared__ u16 t[32][33];
  const int bx = blockIdx.x * 32, by = blockIdx.y * 32;
  const int tx = threadIdx.x & 31, ty = threadIdx.x >> 5;  // 32x8
#pragma unroll
  for (int i = 0; i < 32; i += 8)
    t[ty + i][tx] = f2bf(src[(size_t)(by + ty + i) * C + bx + tx]);
  __syncthreads();
#pragma unroll
  for (int i = 0; i < 32; i += 8)
    dst[(size_t)(bx + ty + i) * R + by + tx] = t[tx][ty + i];
}

// ---------------- mask compaction: idx[b][] = unmasked key positions ----------------
// Deterministic order-preserving prefix sum. 1 block of 512 per batch; 4 keys/thread.
__global__ __launch_bounds__(512) void mask_compact(
    const int* __restrict__ mask, int* __restrict__ idx, int* __restrict__ cnt) {
  const int b = blockIdx.x;
  const int tid = threadIdx.x;
  const int lane = tid & 63, wave = tid >> 6;
  __shared__ int wtot[8];
  int m[4], c = 0;
#pragma unroll
  for (int j = 0; j < 4; ++j) {
    m[j] = (mask[b * 2048 + tid * 4 + j] != 0);
    c += m[j];
  }
  int pfx = c;
#pragma unroll
  for (int sh = 1; sh < 64; sh <<= 1) {
    int v = __shfl_up(pfx, sh);
    if (lane >= sh) pfx += v;
  }
  if (lane == 63) wtot[wave] = pfx;
  int epfx = pfx - c;
  __syncthreads();
  int wbase = 0, total = 0;
#pragma unroll
  for (int w = 0; w < 8; ++w) {
    int v = wtot[w];
    if (w < wave) wbase += v;
    total += v;
  }
  int pos = b * 2048 + wbase + epfx;
#pragma unroll
  for (int j = 0; j < 4; ++j)
    if (m[j]) idx[pos++] = tid * 4 + j;
  for (int i = total + tid; i < 2048; i += 512) idx[b * 2048 + i] = 0;
  if (tid == 0) cnt[b] = total;
}

// ------- qkv GEMM, fused f32->bf16 A, single-barrier pipeline + T2 swizzle -------
__global__ __launch_bounds__(256) void gemm_a32_bf16(
    const float* __restrict__ A, const u16* __restrict__ Bt,
    const float* __restrict__ bias, u16* __restrict__ Cout,
    int M, int N, int K) {
  __shared__ __align__(16) u16 As[2][128 * 64];
  __shared__ __align__(16) u16 Bs[2][128 * 64];
  const int tid = threadIdx.x;
  const int lane = tid & 63;
  const int wave = tid >> 6;
  const int nwg = gridDim.x;
  const int id = blockIdx.x;
  const int sw = (id & 7) * (nwg >> 3) + (id >> 3);
  const int nx = N >> 7;
  const int m0 = (sw / nx) * 128;
  const int n0 = (sw % nx) * 128;
  const int wm = (wave >> 1) * 64;
  const int wn = (wave & 1) * 64;

  f32x4 acc[4][4] = {};
  const char* Bbase = (const char*)Bt;
  float4 fa[4], fb[4];

#define A32_ISSUE_B(ktile, buf)                                                \
  _Pragma("unroll") for (int i = 0; i < 4; ++i) {                              \
    int flat = wave * 1024 + lane * 16 + i * 4096;                             \
    int row = flat >> 7;                                                       \
    int cb = flat & 127;                                                       \
    int scb = cb ^ ((row & 7) << 4);                                           \
    gload_lds16(Bbase + ((size_t)(n0 + row) * K + (ktile)) * 2 + scb,          \
                (char*)&Bs[buf][0] + flat);                                    \
  }

#define A32_LOAD_A(ktile)                                                      \
  _Pragma("unroll") for (int i = 0; i < 4; ++i) {                              \
    int flat = wave * 1024 + lane * 16 + i * 4096;                             \
    int row = flat >> 7;                                                       \
    int cb = flat & 127;                                                       \
    const float* ax = A + (size_t)(m0 + row) * K + (ktile) + (cb >> 1);        \
    fa[i] = *(const float4*)ax;                                                \
    fb[i] = *(const float4*)(ax + 4);                                          \
  }

#define A32_CVT(buf)                                                           \
  _Pragma("unroll") for (int i = 0; i < 4; ++i) {                              \
    int flat = wave * 1024 + lane * 16 + i * 4096;                             \
    int row = flat >> 7;                                                       \
    int cb = flat & 127;                                                       \
    union { u32 w[4]; bf16x8 v; } o;                                           \
    o.w[0] = cvtpk_bf16(fa[i].x, fa[i].y);                                     \
    o.w[1] = cvtpk_bf16(fa[i].z, fa[i].w);                                     \
    o.w[2] = cvtpk_bf16(fb[i].x, fb[i].y);                                     \
    o.w[3] = cvtpk_bf16(fb[i].z, fb[i].w);                                     \
    *(bf16x8*)((char*)&As[buf][0] + row * 128 + (cb ^ ((row & 7) << 4))) = o.v; \
  }

  A32_ISSUE_B(0, 0);
  A32_LOAD_A(0);
  A32_CVT(0);
  asm volatile("s_waitcnt lgkmcnt(0)" ::: "memory");
  BAR();

  const int nsteps = K >> 6;
  for (int t = 0; t < nsteps; ++t) {
    if (t < nsteps - 1) {
      A32_ISSUE_B((t << 6) + 64, (t & 1) ^ 1);
      A32_LOAD_A((t << 6) + 64);
    }
    __builtin_amdgcn_sched_barrier(0);
#pragma unroll
    for (int ks = 0; ks < 2; ++ks) {
      const int col = (lane >> 4) * 8 + ks * 32;
      bf16x8 af[4], bfr[4];
#pragma unroll
      for (int mt = 0; mt < 4; ++mt) {
        int row = wm + mt * 16 + (lane & 15);
        af[mt] = *(const bf16x8*)((const char*)&As[t & 1][0] + row * 128 +
                                  ((col * 2) ^ ((row & 7) << 4)));
      }
#pragma unroll
      for (int nt = 0; nt < 4; ++nt) {
        int row = wn + nt * 16 + (lane & 15);
        bfr[nt] = *(const bf16x8*)((const char*)&Bs[t & 1][0] + row * 128 +
                                   ((col * 2) ^ ((row & 7) << 4)));
      }
#pragma unroll
      for (int mt = 0; mt < 4; ++mt)
#pragma unroll
        for (int nt = 0; nt < 4; ++nt)
          acc[mt][nt] = MFMA16(af[mt], bfr[nt], acc[mt][nt]);
    }
    __builtin_amdgcn_sched_barrier(0);
    if (t < nsteps - 1) {
      A32_CVT((t & 1) ^ 1);
      asm volatile("s_waitcnt lgkmcnt(0)" ::: "memory");
      BAR();
    }
  }
#undef A32_ISSUE_B
#undef A32_LOAD_A
#undef A32_CVT

  float bv[4];
#pragma unroll
  for (int nt = 0; nt < 4; ++nt)
    bv[nt] = bias[n0 + wn + nt * 16 + (lane & 15)];
#pragma unroll
  for (int mt = 0; mt < 4; ++mt)
#pragma unroll
    for (int nt = 0; nt < 4; ++nt)
#pragma unroll
      for (int r = 0; r < 4; ++r) {
        int m = m0 + wm + mt * 16 + (lane >> 4) * 4 + r;
        int n = n0 + wn + nt * 16 + (lane & 15);
        Cout[(size_t)m * N + n] = f2bf(acc[mt][nt][r] + bv[nt]);
      }
}

// ---------------- GEMM (bf16 A), pipelined dbuf + T2 swizzle ----------------
template <bool OUT_BF16>
__global__ __launch_bounds__(256) void gemm_bf16(
    const u16* __restrict__ A, const u16* __restrict__ Bt,
    const float* __restrict__ bias, void* __restrict__ Cout,
    int M, int N, int K) {
  __shared__ __align__(16) u16 As[2][128 * 64];
  __shared__ __align__(16) u16 Bs[2][128 * 64];
  const int tid = threadIdx.x;
  const int lane = tid & 63;
  const int wave = tid >> 6;
  const int nwg = gridDim.x;
  const int id = blockIdx.x;
  const int sw = (id & 7) * (nwg >> 3) + (id >> 3);
  const int nx = N >> 7;
  const int m0 = (sw / nx) * 128;
  const int n0 = (sw % nx) * 128;
  const int wm = (wave >> 1) * 64;
  const int wn = (wave & 1) * 64;

  f32x4 acc[4][4] = {};

  const char* Abase = (const char*)A;
  const char* Bbase = (const char*)Bt;

#define STAGE_AB(ktile, buf)                                                   \
  _Pragma("unroll") for (int i = 0; i < 4; ++i) {                              \
    int flat = wave * 1024 + lane * 16 + i * 4096;                             \
    int row = flat >> 7;                                                       \
    int cb = flat & 127;                                                       \
    int scb = cb ^ ((row & 7) << 4);                                           \
    gload_lds16(Abase + ((size_t)(m0 + row) * K + (ktile)) * 2 + scb,          \
                (char*)&As[buf][0] + flat);                                    \
    gload_lds16(Bbase + ((size_t)(n0 + row) * K + (ktile)) * 2 + scb,          \
                (char*)&Bs[buf][0] + flat);                                    \
  }

  STAGE_AB(0, 0);

  const int nsteps = K >> 6;
  for (int t = 0; t < nsteps; ++t) {
    asm volatile("s_waitcnt vmcnt(0)" ::: "memory");
    BAR();
    if (t < nsteps - 1) STAGE_AB((t << 6) + 64, (t & 1) ^ 1);
#pragma unroll
    for (int ks = 0; ks < 2; ++ks) {
      const int col = (lane >> 4) * 8 + ks * 32;
      bf16x8 af[4], bfr[4];
#pragma unroll
      for (int mt = 0; mt < 4; ++mt) {
        int row = wm + mt * 16 + (lane & 15);
        af[mt] = *(const bf16x8*)((const char*)&As[t & 1][0] + row * 128 +
                                  ((col * 2) ^ ((row & 7) << 4)));
      }
#pragma unroll
      for (int nt = 0; nt < 4; ++nt) {
        int row = wn + nt * 16 + (lane & 15);
        bfr[nt] = *(const bf16x8*)((const char*)&Bs[t & 1][0] + row * 128 +
                                   ((col * 2) ^ ((row & 7) << 4)));
      }
#pragma unroll
      for (int mt = 0; mt < 4; ++mt)
#pragma unroll
        for (int nt = 0; nt < 4; ++nt)
          acc[mt][nt] = MFMA16(af[mt], bfr[nt], acc[mt][nt]);
    }
  }
#undef STAGE_AB

  float bv[4];
#pragma unroll
  for (int nt = 0; nt < 4; ++nt)
    bv[nt] = bias[n0 + wn + nt * 16 + (lane & 15)];
#pragma unroll
  for (int mt = 0; mt < 4; ++mt)
#pragma unroll
    for (int nt = 0; nt < 4; ++nt)
#pragma unroll
      for (int r = 0; r < 4; ++r) {
        int m = m0 + wm + mt * 16 + (lane >> 4) * 4 + r;
        int n = n0 + wn + nt * 16 + (lane & 15);
        float v = acc[mt][nt][r] + bv[nt];
        if (OUT_BF16)
          ((u16*)Cout)[(size_t)m * N + n] = f2bf(v);
        else
          ((float*)Cout)[(size_t)m * N + n] = v;
      }
}

// ---------------- flash attention (v13: COMPACTED keys via idx gather) ----------
// Only unmasked keys (~50%) are processed: idx[b][]=unmasked positions, cnt[b].
// m=0 softmax is permutation-invariant & subset-exact, so compaction is exact.
// Tail tile: positions >= cnt get V=0 (accO) and mask-frag 0 (ssum) via lut.
// Permuted-K staging (zero-shuffle PV) + XCD-affinity grid kept unchanged.
#define T_SEQ 2048
#define ROWQKV 3072
#define SCL 0.180336880f  /* (1/sqrt(64)) * log2(e) */

template <bool SPLIT>
__global__ __launch_bounds__(512) void attn_fwd(
    const u16* __restrict__ qkv, const int* __restrict__ idx,
    const int* __restrict__ cnt, u16* __restrict__ outp,
    float* __restrict__ Ml) {
  __shared__ __align__(16) u16 Ks[2][2][64 * 64];  // [buf][half][storerow][dk], swz s=row&7
  __shared__ __align__(16) u16 Vt[2][2][64 * 64];  // [buf][half][d][cpos], swz row^(row>>3)
  __shared__ __align__(16) u32 lut[256 * 4];       // byte -> 8 x bf16 {0,1}

  const int tid = threadIdx.x;
  const int lane = tid & 63;
  const int wave = tid >> 6;
  const int r15 = lane & 15;
  const int g = lane >> 4;
  const int id = blockIdx.x;
  const int hz = ((id >> 6) << 3) | (id & 7);
  const int qb = (id >> 3) & 7;
  const int h = SPLIT ? (hz >> 2) : (hz >> 1);
  const int z = SPLIT ? (hz & 3) : (hz & 1);
  const int split = SPLIT ? (z >> 1) : 0;
  const int b = SPLIT ? (z & 1) : z;
  const int q0 = qb * 256 + wave * 32;
  const size_t rowb = (size_t)b * T_SEQ;
  const int* idxb = idx + b * 2048;
  const int count = cnt[b];
  const int ntot = (count + 127) >> 7;
  const int nth = (ntot + 1) >> 1;
  const int t0 = (SPLIT && split) ? nth : 0;
  const int nt2 = SPLIT ? (split ? ntot - nth : nth) : ntot;

  for (int i = tid; i < 256; i += 512) {
    union { u32 w[4]; bf16x8 v; } e;
#pragma unroll
    for (int j = 0; j < 4; ++j)
      e.w[j] = (((i >> (2 * j)) & 1) ? 0x3F80u : 0u) |
               (((i >> (2 * j + 1)) & 1) ? 0x3F800000u : 0u);
    *(bf16x8*)((char*)lut + i * 16) = e.v;
  }

  bf16x8 aq[2][2];
#pragma unroll
  for (int mt = 0; mt < 2; ++mt)
#pragma unroll
    for (int ks = 0; ks < 2; ++ks) {
      bf16x8 t = *(const bf16x8*)(qkv +
          (rowb + q0 + mt * 16 + r15) * ROWQKV + h * 64 + g * 8 + ks * 32);
#pragma unroll
      for (int j = 0; j < 8; ++j) t[j] = (short)f2bf(bf2f((u16)t[j]) * SCL);
      aq[mt][ks] = t;
    }

  f32x4 accO[2][4] = {};
  f32x4 ssum[2] = {};
  bf16x8 vr0, vr1;

// stage 128 compact keys of K (permuted rows) into both halves of buf
#define ISSUE_K2(ct, buf)                                                      \
  {                                                                            \
    int L = wave * 1024 + lane * 16;                                           \
    int row = L >> 7;                                                          \
    int cb = L & 127;                                                          \
    int scb = cb ^ ((row & 7) << 4);                                           \
    int prow = ((row >> 4) & 1) * 32 + ((row >> 2) & 3) * 8 +                  \
               (row >> 5) * 4 + (row & 3);                                     \
    int gk0 = idxb[(ct) * 128 + prow];                                         \
    int gk1 = idxb[(ct) * 128 + 64 + prow];                                    \
    gload_lds16((const char*)qkv +                                             \
                    ((rowb + gk0) * ROWQKV + 1024 + h * 64) * 2 + scb,         \
                (char*)&Ks[buf][0][0] + wave * 1024);                          \
    gload_lds16((const char*)qkv +                                             \
                    ((rowb + gk1) * ROWQKV + 1024 + h * 64) * 2 + scb,         \
                (char*)&Ks[buf][1][0] + wave * 1024);                          \
  }

#define LOAD_V2(ct)                                                            \
  {                                                                            \
    int key = tid >> 3;                                                        \
    int gv0 = idxb[(ct) * 128 + key];                                          \
    int gv1 = idxb[(ct) * 128 + 64 + key];                                     \
    vr0 = *(const bf16x8*)(qkv + (rowb + gv0) * ROWQKV + 2048 + h * 64 +       \
                           (tid & 7) * 8);                                     \
    vr1 = *(const bf16x8*)(qkv + (rowb + gv1) * ROWQKV + 2048 + h * 64 +       \
                           (tid & 7) * 8);                                     \
  }

// zero V for pad positions (compact pos >= count): tail tile only
#define WRITE_V2(buf, ct)                                                      \
  {                                                                            \
    int key = tid >> 3;                                                        \
    if ((ct) * 128 + key >= count) {                                           \
      bf16x8 zz = {};                                                          \
      vr0 = zz;                                                                \
    }                                                                          \
    if ((ct) * 128 + 64 + key >= count) {                                      \
      bf16x8 zz = {};                                                          \
      vr1 = zz;                                                                \
    }                                                                          \
    _Pragma("unroll") for (int j = 0; j < 8; ++j) {                            \
      int row = (tid & 7) * 8 + j;                                             \
      int sv = ((row ^ (row >> 3)) & 7) << 4;                                  \
      *(u16*)((char*)&Vt[buf][0][0] + row * 128 + ((key * 2) ^ sv)) =          \
          (u16)vr0[j];                                                         \
      *(u16*)((char*)&Vt[buf][1][0] + row * 128 + ((key * 2) ^ sv)) =          \
          (u16)vr1[j];                                                         \
    }                                                                          \
  }

#define COMPUTE_HALF(H, ct)                                                    \
  {                                                                            \
    f32x4 s[2][4] = {};                                                        \
    _Pragma("unroll") for (int ks = 0; ks < 2; ++ks) {                         \
      bf16x8 bk[4];                                                            \
      _Pragma("unroll") for (int nt = 0; nt < 4; ++nt) {                       \
        int row = nt * 16 + r15;                                               \
        int cb = (g * 8 + ks * 32) * 2;                                        \
        bk[nt] = *(const bf16x8*)((const char*)&Ks[cur][H][0] + row * 128 +    \
                                  (cb ^ ((row & 7) << 4)));                    \
      }                                                                        \
      _Pragma("unroll") for (int mt = 0; mt < 2; ++mt)                         \
        _Pragma("unroll") for (int nt = 0; nt < 4; ++nt)                       \
          s[mt][nt] = MFMA16(bk[nt], aq[mt][ks], s[mt][nt]);                   \
    }                                                                          \
    u32 pk[2][4][2];                                                           \
    _Pragma("unroll") for (int mt = 0; mt < 2; ++mt)                           \
      _Pragma("unroll") for (int nt = 0; nt < 4; ++nt) {                       \
        float e0 = exp2f(s[mt][nt][0]);                                        \
        float e1 = exp2f(s[mt][nt][1]);                                        \
        float e2 = exp2f(s[mt][nt][2]);                                        \
        float e3 = exp2f(s[mt][nt][3]);                                        \
        pk[mt][nt][0] = cvtpk_bf16(e0, e1);                                    \
        pk[mt][nt][1] = cvtpk_bf16(e2, e3);                                    \
      }                                                                        \
    __builtin_amdgcn_s_setprio(1);                                             \
    _Pragma("unroll") for (int ks = 0; ks < 2; ++ks) {                         \
      const int col = g * 8 + ks * 32;                                         \
      bf16x8 bv[4];                                                            \
      _Pragma("unroll") for (int nt = 0; nt < 4; ++nt) {                       \
        int row = nt * 16 + r15;                                               \
        int sv = ((row ^ (row >> 3)) & 7) << 4;                                \
        bv[nt] = *(const bf16x8*)((const char*)&Vt[cur][H][0] + row * 128 +    \
                                  ((col * 2) ^ sv));                           \
      }                                                                        \
      int rbase = count - ((ct) * 128 + (H) * 64 + ks * 32 + g * 8);           \
      int rr = rbase < 0 ? 0 : (rbase > 8 ? 8 : rbase);                        \
      u32 lb = (1u << rr) - 1u;                                                \
      bf16x8 mf = *(const bf16x8*)((const char*)lut + lb * 16);                \
      _Pragma("unroll") for (int mt = 0; mt < 2; ++mt) {                       \
        union { u32 w[4]; bf16x8 v; } ap;                                      \
        ap.w[0] = pk[mt][ks][0];                                               \
        ap.w[1] = pk[mt][ks][1];                                               \
        ap.w[2] = pk[mt][2 + ks][0];                                           \
        ap.w[3] = pk[mt][2 + ks][1];                                           \
        _Pragma("unroll") for (int nt = 0; nt < 4; ++nt)                       \
          accO[mt][nt] = MFMA16(ap.v, bv[nt], accO[mt][nt]);                   \
        ssum[mt] = MFMA16(ap.v, mf, ssum[mt]);                                 \
      }                                                                        \
    }                                                                          \
    __builtin_amdgcn_s_setprio(0);                                             \
  }

  if (nt2 > 0) {
    // prologue
    ISSUE_K2(t0, 0);
    LOAD_V2(t0);
    __syncthreads();  // lut visible + tile-0 K staged (implicit waits)
    WRITE_V2(0, t0);
    asm volatile("s_waitcnt lgkmcnt(0)" ::: "memory");
    BAR();

    int cur = 0;
    for (int t = 0; t < nt2; ++t) {
      const int ct = t0 + t;
      if (t < nt2 - 1) {
        ISSUE_K2(ct + 1, cur ^ 1);
        LOAD_V2(ct + 1);
      }

      COMPUTE_HALF(0, ct);
      COMPUTE_HALF(1, ct);

      if (t < nt2 - 1) {
        asm volatile("s_waitcnt vmcnt(0)" ::: "memory");
        WRITE_V2(cur ^ 1, ct + 1);
        asm volatile("s_waitcnt lgkmcnt(0)" ::: "memory");
        BAR();
        cur ^= 1;
      }
    }
  }

  if (SPLIT) {
    u16* po = outp + (size_t)split * T_SEQ * 2 * 1024;
#pragma unroll
    for (int mt = 0; mt < 2; ++mt) {
#pragma unroll
      for (int r = 0; r < 4; ++r) {
        int q = q0 + mt * 16 + g * 4 + r;
#pragma unroll
        for (int nt = 0; nt < 4; ++nt)
          po[(rowb + q) * 1024 + h * 64 + nt * 16 + r15] = f2bf(accO[mt][nt][r]);
      }
      if (r15 == 0) {
        int idxm = ((split * 2 + b) * 16 + h) * T_SEQ + q0 + mt * 16 + g * 4;
        *(f32x4*)(Ml + idxm) = ssum[mt];
      }
    }
  } else {
#pragma unroll
    for (int mt = 0; mt < 2; ++mt)
#pragma unroll
      for (int r = 0; r < 4; ++r) {
        float inv = 1.f / ssum[mt][r];
        int q = q0 + mt * 16 + g * 4 + r;
#pragma unroll
        for (int nt = 0; nt < 4; ++nt)
          outp[(rowb + q) * 1024 + h * 64 + nt * 16 + r15] =
              f2bf(accO[mt][nt][r] * inv);
      }
  }
#undef ISSUE_K2
#undef LOAD_V2
#undef WRITE_V2
#undef COMPUTE_HALF
}

// ---------------- combine two KV-splits (m=0: just l0+l1) ----------------
__global__ __launch_bounds__(256) void attn_combine(
    const u16* __restrict__ part, const float* __restrict__ Ml,
    u16* __restrict__ att) {
  int idx = blockIdx.x * 256 + threadIdx.x;  // (B*T)*(H/8) = 524288
  int row = idx >> 7;                        // b*2048 + q
  int c8 = idx & 127;
  int col = c8 * 8;
  int h = c8 >> 3;
  int b = row >> 11, q = row & 2047;
  float l0 = Ml[(b * 16 + h) * T_SEQ + q];
  float l1 = Ml[((2 + b) * 16 + h) * T_SEQ + q];
  float inv = 1.f / (l0 + l1);
  bf16x8 o0 = *(const bf16x8*)(part + (size_t)row * 1024 + col);
  bf16x8 o1 = *(const bf16x8*)(part + (size_t)T_SEQ * 2 * 1024 +
                               (size_t)row * 1024 + col);
  bf16x8 o;
#pragma unroll
  for (int j = 0; j < 8; ++j)
    o[j] = (short)f2bf((bf2f((u16)o0[j]) + bf2f((u16)o1[j])) * inv);
  *(bf16x8*)(att + (size_t)row * 1024 + col) = o;
}

// ---------------- launch ----------------
extern "C" void kernel_launch(void* const* d_in, const int* in_sizes, int n_in,
                              void* d_out, int out_size, void* d_ws, size_t ws_size,
                              hipStream_t stream) {
  const float* x = (const float*)d_in[0];     // [2,2048,1024] f32
  const int* mask = (const int*)d_in[1];      // [2,1,1,2048] int32
  const float* Wqkv = (const float*)d_in[2];  // [1024,3072] f32
  const float* bqkv = (const float*)d_in[3];  // [3072] f32
  const float* Wout = (const float*)d_in[4];  // [1024,1024] f32
  const float* bout = (const float*)d_in[5];  // [1024] f32
  float* out = (float*)d_out;                 // [2,2048,1024] f32

  const int B = 2, T = 2048, H = 1024, M = B * T;

  u16* qkv = (u16*)d_ws;                       // M*3H
  u16* att = qkv + (size_t)M * 3 * H;          // M*H
  u16* WtQ = att + (size_t)M * H;              // 3H*H
  u16* WtO = WtQ + (size_t)3 * H * H;          // H*H
  u16* part = WtO + (size_t)H * H;             // 2 * M*H  (split partials)
  float* Ml = (float*)(part + (size_t)2 * M * H);  // 2*131072 floats
  int* idxb = (int*)(Ml + (size_t)2 * 131072);     // B*T ints
  int* cntb = idxb + B * T;                        // B ints

  const size_t need = ((size_t)M * 3 * H + (size_t)M * H + (size_t)3 * H * H +
                       (size_t)H * H + (size_t)2 * M * H) * 2 +
                      (size_t)2 * 131072 * 4 + (size_t)(B * T + 8) * 4;
  const bool split = ws_size >= need;

  transpose_f32_bf16<<<dim3(3 * H / 32, H / 32), 256, 0, stream>>>(Wqkv, WtQ, H, 3 * H);
  transpose_f32_bf16<<<dim3(H / 32, H / 32), 256, 0, stream>>>(Wout, WtO, H, H);
  mask_compact<<<B, 512, 0, stream>>>(mask, idxb, cntb);
  gemm_a32_bf16<<<(3 * H / 128) * (M / 128), 256, 0, stream>>>(x, WtQ, bqkv, qkv, M, 3 * H, H);
  if (split) {
    attn_fwd<true><<<512, 512, 0, stream>>>(qkv, idxb, cntb, part, Ml);
    attn_combine<<<(M * H / 8 + 255) / 256, 256, 0, stream>>>(part, Ml, att);
  } else {
    attn_fwd<false><<<256, 512, 0, stream>>>(qkv, idxb, cntb, att, Ml);
  }
  gemm_bf16<false><<<(H / 128) * (M / 128), 256, 0, stream>>>(att, WtO, bout, out, M, H, H);
}